// Round 1
// baseline (309.553 us; speedup 1.0000x reference)
//
#include <hip/hip_runtime.h>

// Problem constants (UserContextAttentionPooler): U=128, I=256, J=512, C=E=128
#define UU 128
#define II 256
#define JJ 512
#define CC 128
#define EE 128
#define IB 16            // i-rows per block
#define NIB (II / IB)    // 16 blocks per u
#define PROW (JJ + 4)    // padded LDS row (breaks bank aliasing on p reads)

__device__ __forceinline__ float fast_tanh(float x) {
    // tanh(x) = 1 - 2/(exp(2x)+1); saturates cleanly at +-1 (no inf/inf NaN)
    float ex = __expf(2.0f * x);
    return 1.0f - 2.0f / (ex + 1.0f);
}

__device__ __forceinline__ float wave_reduce_add(float v) {
#pragma unroll
    for (int k = 32; k >= 1; k >>= 1) v += __shfl_xor(v, k, 64);
    return v;
}

// ---------------------------------------------------------------------------
// Kernel A: precompute s_t (U,I) [+b_dense], s_k (U,J), u_part (U,C) [+b_mlp]
// ---------------------------------------------------------------------------
__global__ void precompute_kernel(const float* __restrict__ tgt,
                                  const float* __restrict__ itc,
                                  const float* __restrict__ user,
                                  const float* __restrict__ wd,
                                  const float* __restrict__ bd,
                                  const float* __restrict__ Wm,
                                  const float* __restrict__ bm,
                                  float* __restrict__ st_g,
                                  float* __restrict__ sk_g,
                                  float* __restrict__ up_g) {
    const int ST_BLOCKS = UU * II / 4;  // 8192 (wave per row, 4 waves/block)
    const int SK_BLOCKS = UU * JJ / 4;  // 16384
    int b = blockIdx.x;
    int t = threadIdx.x;
    if (b < ST_BLOCKS) {
        int row = b * 4 + (t >> 6);
        int lane = t & 63;
        float2 a = *(const float2*)&tgt[(size_t)row * CC + lane * 2];
        float2 w = *(const float2*)&wd[lane * 2];
        float s = wave_reduce_add(a.x * w.x + a.y * w.y);
        if (lane == 0) st_g[row] = s + bd[0];
    } else if (b < ST_BLOCKS + SK_BLOCKS) {
        int row = (b - ST_BLOCKS) * 4 + (t >> 6);
        int lane = t & 63;
        float2 a = *(const float2*)&itc[(size_t)row * CC + lane * 2];
        float2 w = *(const float2*)&wd[CC + lane * 2];
        float s = wave_reduce_add(a.x * w.x + a.y * w.y);
        if (lane == 0) sk_g[row] = s;
    } else {
        int idx = (b - ST_BLOCKS - SK_BLOCKS) * 256 + t;  // < U*C
        int u = idx >> 7, c = idx & 127;
        float acc = bm[c];
#pragma unroll 8
        for (int e = 0; e < EE; ++e) acc += user[u * EE + e] * Wm[e * CC + c];
        up_g[idx] = acc;
    }
}

// ---------------------------------------------------------------------------
// Kernel B: fused scores -> softmax -> attn write -> pooled GEMM -> mlp
// One block per (u, 16-row i-tile). 256 threads = 4 waves. ~36KB LDS.
// ---------------------------------------------------------------------------
template <bool PRE>
__global__ __launch_bounds__(256, 4) void fused_kernel(
    const float* __restrict__ tgt, const float* __restrict__ itc,
    const float* __restrict__ user, const int* __restrict__ mask,
    const float* __restrict__ wd, const float* __restrict__ bd,
    const float* __restrict__ Wm, const float* __restrict__ bm,
    const float* __restrict__ st_g, const float* __restrict__ sk_g,
    const float* __restrict__ up_g, float* __restrict__ out_ctx,
    float* __restrict__ out_attn) {
    __shared__ float p[IB][PROW];   // scores->probs; later reused as pooled[16][128]
    __shared__ float skv[JJ];
    __shared__ float stv[IB];
    __shared__ float upv[CC];
    __shared__ float dinv[IB];
    __shared__ unsigned char mk[JJ];

    // XCD-aware swizzle: all 16 blocks of a given u land on XCD u%8
    int b = blockIdx.x;
    int x = b & 7, q = b >> 3;
    int u = x + 8 * (q >> 4);  // q / NIB
    int ib = q & 15;           // q % NIB
    int i0 = ib * IB;
    int t = threadIdx.x;

    mk[t] = (unsigned char)(mask[u * JJ + t] != 0);
    mk[t + 256] = (unsigned char)(mask[u * JJ + t + 256] != 0);

    if (PRE) {
        skv[t] = sk_g[u * JJ + t];
        skv[t + 256] = sk_g[u * JJ + t + 256];
        if (t < IB) stv[t] = st_g[u * II + i0 + t];
        if (t >= 128) upv[t - 128] = up_g[u * CC + (t - 128)];
    } else {
        int lane = t & 63, w = t >> 6;
        float2 w2 = *(const float2*)&wd[CC + lane * 2];
        for (int r = w; r < JJ; r += 4) {
            float2 a = *(const float2*)&itc[((size_t)u * JJ + r) * CC + lane * 2];
            float s = wave_reduce_add(a.x * w2.x + a.y * w2.y);
            if (lane == 0) skv[r] = s;
        }
        float2 w1 = *(const float2*)&wd[lane * 2];
        float bdv = bd[0];
        for (int r = w; r < IB; r += 4) {
            float2 a = *(const float2*)&tgt[((size_t)u * II + i0 + r) * CC + lane * 2];
            float s = wave_reduce_add(a.x * w1.x + a.y * w1.y);
            if (lane == 0) stv[r] = s + bdv;
        }
        if (t < CC) {
            float acc = bm[t];
            for (int e = 0; e < EE; ++e) acc += user[u * EE + e] * Wm[e * CC + t];
            upv[t] = acc;
        }
    }
    __syncthreads();

    // Phase 1: p = mask ? exp(tanh(st+sk)) : 0   (tanh<=1 so exp can't overflow;
    // masked entries are exactly 0, matching ref's exp(tanh-1e7-max) underflow)
#pragma unroll
    for (int e = 0; e < 8; ++e) {
        int qq = t + e * 256;
        int il = qq >> 7, j = (qq & 127) * 4;
        float s = stv[il];
        float4 sk4 = *(const float4*)&skv[j];
        float4 pv;
        pv.x = mk[j + 0] ? __expf(fast_tanh(s + sk4.x)) : 0.0f;
        pv.y = mk[j + 1] ? __expf(fast_tanh(s + sk4.y)) : 0.0f;
        pv.z = mk[j + 2] ? __expf(fast_tanh(s + sk4.z)) : 0.0f;
        pv.w = mk[j + 3] ? __expf(fast_tanh(s + sk4.w)) : 0.0f;
        *(float4*)&p[il][j] = pv;
    }
    __syncthreads();

    // Phase 2: denom per row -> dinv
    {
        int r = t >> 4, seg = t & 15;
        float sum = 0.f;
#pragma unroll
        for (int kk = 0; kk < 8; ++kk) {
            float4 v = *(const float4*)&p[r][seg * 4 + kk * 64];
            sum += v.x + v.y + v.z + v.w;
        }
#pragma unroll
        for (int k = 8; k >= 1; k >>= 1) sum += __shfl_xor(sum, k, 64);
        if (seg == 0) dinv[r] = 1.0f / sum;
    }
    __syncthreads();

    // Phase 3: write attn = p * dinv (coalesced float4)
    float* attn_base = out_attn + ((size_t)u * II + i0) * JJ;
#pragma unroll
    for (int e = 0; e < 8; ++e) {
        int qq = t + e * 256;
        int il = qq >> 7, j = (qq & 127) * 4;
        float di = dinv[il];
        float4 v = *(const float4*)&p[il][j];
        v.x *= di; v.y *= di; v.z *= di; v.w *= di;
        *(float4*)&attn_base[(size_t)il * JJ + j] = v;
    }

    // Phase 4: pooled = p @ V[u]   (thread owns row ty, cols tx*8..tx*8+7)
    int tx = t & 15, ty = t >> 4;
    const float* Vu = itc + (size_t)u * JJ * CC;
    float acc[8];
#pragma unroll
    for (int k = 0; k < 8; ++k) acc[k] = 0.f;
    for (int j = 0; j < JJ; j += 4) {
        float4 pr = *(const float4*)&p[ty][j];
        float pp[4] = {pr.x, pr.y, pr.z, pr.w};
#pragma unroll
        for (int jj = 0; jj < 4; ++jj) {
            float4 v0 = *(const float4*)&Vu[(size_t)(j + jj) * CC + tx * 8];
            float4 v1 = *(const float4*)&Vu[(size_t)(j + jj) * CC + tx * 8 + 4];
            float pj = pp[jj];
            acc[0] += pj * v0.x; acc[1] += pj * v0.y;
            acc[2] += pj * v0.z; acc[3] += pj * v0.w;
            acc[4] += pj * v1.x; acc[5] += pj * v1.y;
            acc[6] += pj * v1.z; acc[7] += pj * v1.w;
        }
    }
    {
        float di = dinv[ty];
#pragma unroll
        for (int k = 0; k < 8; ++k) acc[k] *= di;
    }

    __syncthreads();  // all p reads done; reuse p LDS as pooled[16][128]
    float* pool = &p[0][0];
    *(float4*)&pool[ty * CC + tx * 8] = make_float4(acc[0], acc[1], acc[2], acc[3]);
    *(float4*)&pool[ty * CC + tx * 8 + 4] = make_float4(acc[4], acc[5], acc[6], acc[7]);
    __syncthreads();

    // Phase 5: out = relu(u_part + pooled @ W_mlp[E:] )   (u_part has b_mlp folded)
    float o[8];
#pragma unroll
    for (int k = 0; k < 8; ++k) o[k] = 0.f;
    for (int k = 0; k < CC; ++k) {
        float pk = pool[ty * CC + k];
        float4 w0 = *(const float4*)&Wm[(size_t)(EE + k) * CC + tx * 8];
        float4 w1 = *(const float4*)&Wm[(size_t)(EE + k) * CC + tx * 8 + 4];
        o[0] += pk * w0.x; o[1] += pk * w0.y; o[2] += pk * w0.z; o[3] += pk * w0.w;
        o[4] += pk * w1.x; o[5] += pk * w1.y; o[6] += pk * w1.z; o[7] += pk * w1.w;
    }
    float4 up0 = *(const float4*)&upv[tx * 8];
    float4 up1 = *(const float4*)&upv[tx * 8 + 4];
    float4 r0, r1;
    r0.x = fmaxf(o[0] + up0.x, 0.f); r0.y = fmaxf(o[1] + up0.y, 0.f);
    r0.z = fmaxf(o[2] + up0.z, 0.f); r0.w = fmaxf(o[3] + up0.w, 0.f);
    r1.x = fmaxf(o[4] + up1.x, 0.f); r1.y = fmaxf(o[5] + up1.y, 0.f);
    r1.z = fmaxf(o[6] + up1.z, 0.f); r1.w = fmaxf(o[7] + up1.w, 0.f);
    float* ctx = out_ctx + ((size_t)u * II + i0 + ty) * CC + tx * 8;
    *(float4*)&ctx[0] = r0;
    *(float4*)&ctx[4] = r1;
}

// ---------------------------------------------------------------------------
extern "C" void kernel_launch(void* const* d_in, const int* in_sizes, int n_in,
                              void* d_out, int out_size, void* d_ws,
                              size_t ws_size, hipStream_t stream) {
    const float* tgt  = (const float*)d_in[0];
    const float* itc  = (const float*)d_in[1];
    const float* user = (const float*)d_in[2];
    const int*   mask = (const int*)d_in[3];
    const float* wd   = (const float*)d_in[4];
    const float* bd   = (const float*)d_in[5];
    const float* Wm   = (const float*)d_in[6];
    const float* bm   = (const float*)d_in[7];
    float* out_ctx  = (float*)d_out;
    float* out_attn = out_ctx + (size_t)UU * II * CC;

    size_t need = (size_t)(UU * II + UU * JJ + UU * CC) * sizeof(float);
    if (ws_size >= need) {
        float* st_g = (float*)d_ws;
        float* sk_g = st_g + UU * II;
        float* up_g = sk_g + UU * JJ;
        int gridA = UU * II / 4 + UU * JJ / 4 + UU * CC / 256;
        precompute_kernel<<<gridA, 256, 0, stream>>>(tgt, itc, user, wd, bd, Wm,
                                                     bm, st_g, sk_g, up_g);
        fused_kernel<true><<<UU * NIB, 256, 0, stream>>>(
            tgt, itc, user, mask, wd, bd, Wm, bm, st_g, sk_g, up_g, out_ctx,
            out_attn);
    } else {
        fused_kernel<false><<<UU * NIB, 256, 0, stream>>>(
            tgt, itc, user, mask, wd, bd, Wm, bm, nullptr, nullptr, nullptr,
            out_ctx, out_attn);
    }
}

// Round 2
// 157.655 us; speedup vs baseline: 1.9635x; 1.9635x over previous
//
#include <hip/hip_runtime.h>

// Problem constants (UserContextAttentionPooler): U=128, I=256, J=512, C=E=128
#define UU 128
#define II 256
#define JJ 512
#define CC 128
#define EE 128
#define IB 16            // i-rows per block
#define NIB (II / IB)    // 16 blocks per u
#define JT 64            // j-tile for V staging
#define VTP 72           // Vt row stride in shorts (144B = 36 dw == 4 mod 32)

typedef short bf16x8 __attribute__((ext_vector_type(8)));
typedef float f32x4 __attribute__((ext_vector_type(4)));

union FragU { bf16x8 v; unsigned u[4]; };

__device__ __forceinline__ float fast_tanh(float x) {
    float ex = __expf(2.0f * x);
    return 1.0f - 2.0f / (ex + 1.0f);
}

__device__ __forceinline__ unsigned pack_bf16x2(float lo, float hi) {
    unsigned ul = __float_as_uint(lo), uh = __float_as_uint(hi);
    ul = (ul + 0x7FFFu + ((ul >> 16) & 1u)) >> 16;
    uh = (uh + 0x7FFFu + ((uh >> 16) & 1u)) >> 16;
    return ul | (uh << 16);
}

__device__ __forceinline__ float wave_reduce_add(float v) {
#pragma unroll
    for (int k = 32; k >= 1; k >>= 1) v += __shfl_xor(v, k, 64);
    return v;
}

// ---------------------------------------------------------------------------
// Kernel A: precompute s_t (U,I) [+b_dense], s_k (U,J), u_part (U,C) [+b_mlp]
// ---------------------------------------------------------------------------
__global__ void precompute_kernel(const float* __restrict__ tgt,
                                  const float* __restrict__ itc,
                                  const float* __restrict__ user,
                                  const float* __restrict__ wd,
                                  const float* __restrict__ bd,
                                  const float* __restrict__ Wm,
                                  const float* __restrict__ bm,
                                  float* __restrict__ st_g,
                                  float* __restrict__ sk_g,
                                  float* __restrict__ up_g) {
    const int ST_BLOCKS = UU * II / 4;
    const int SK_BLOCKS = UU * JJ / 4;
    int b = blockIdx.x;
    int t = threadIdx.x;
    if (b < ST_BLOCKS) {
        int row = b * 4 + (t >> 6);
        int lane = t & 63;
        float2 a = *(const float2*)&tgt[(size_t)row * CC + lane * 2];
        float2 w = *(const float2*)&wd[lane * 2];
        float s = wave_reduce_add(a.x * w.x + a.y * w.y);
        if (lane == 0) st_g[row] = s + bd[0];
    } else if (b < ST_BLOCKS + SK_BLOCKS) {
        int row = (b - ST_BLOCKS) * 4 + (t >> 6);
        int lane = t & 63;
        float2 a = *(const float2*)&itc[(size_t)row * CC + lane * 2];
        float2 w = *(const float2*)&wd[CC + lane * 2];
        float s = wave_reduce_add(a.x * w.x + a.y * w.y);
        if (lane == 0) sk_g[row] = s;
    } else {
        int idx = (b - ST_BLOCKS - SK_BLOCKS) * 256 + t;
        int u = idx >> 7, c = idx & 127;
        float acc = bm[c];
#pragma unroll 8
        for (int e = 0; e < EE; ++e) acc += user[u * EE + e] * Wm[e * CC + c];
        up_g[idx] = acc;
    }
}

// ---------------------------------------------------------------------------
// Kernel B: fused scores -> softmax -> attn write -> MFMA pooled -> mlp
// One block per (u, 16-row i-tile). 256 threads = 4 waves.
// A-frags (p in bf16) built in registers; V staged transposed bf16 in LDS.
// ---------------------------------------------------------------------------
template <bool PRE>
__global__ __launch_bounds__(256, 3) void fused_kernel(
    const float* __restrict__ tgt, const float* __restrict__ itc,
    const float* __restrict__ user, const int* __restrict__ mask,
    const float* __restrict__ wd, const float* __restrict__ bd,
    const float* __restrict__ Wm, const float* __restrict__ bm,
    const float* __restrict__ st_g, const float* __restrict__ sk_g,
    const float* __restrict__ up_g, float* __restrict__ out_ctx,
    float* __restrict__ out_attn) {
    __shared__ __align__(16) short Vt[CC][VTP];     // V tile, transposed, bf16
    __shared__ __align__(16) float pool[IB][CC + 4];
    __shared__ __align__(16) float skv[JJ];
    __shared__ __align__(16) float stv[IB];
    __shared__ __align__(16) float upv[CC];
    __shared__ __align__(16) float dinv_lds[IB];
    __shared__ unsigned char mk[JJ];

    // XCD-aware swizzle: all 16 blocks of a given u land on XCD u%8
    int b = blockIdx.x;
    int x = b & 7, q = b >> 3;
    int u = x + 8 * (q >> 4);
    int ib = q & 15;
    int i0 = ib * IB;
    int t = threadIdx.x;

    mk[t] = (unsigned char)(mask[u * JJ + t] != 0);
    mk[t + 256] = (unsigned char)(mask[u * JJ + t + 256] != 0);

    if (PRE) {
        skv[t] = sk_g[u * JJ + t];
        skv[t + 256] = sk_g[u * JJ + t + 256];
        if (t < IB) stv[t] = st_g[u * II + i0 + t];
        if (t >= 128) upv[t - 128] = up_g[u * CC + (t - 128)];
    } else {
        int lane = t & 63, w4 = t >> 6;
        float2 w2 = *(const float2*)&wd[CC + lane * 2];
        for (int r = w4; r < JJ; r += 4) {
            float2 a = *(const float2*)&itc[((size_t)u * JJ + r) * CC + lane * 2];
            float s = wave_reduce_add(a.x * w2.x + a.y * w2.y);
            if (lane == 0) skv[r] = s;
        }
        float2 w1 = *(const float2*)&wd[lane * 2];
        float bdv = bd[0];
        for (int r = w4; r < IB; r += 4) {
            float2 a = *(const float2*)&tgt[((size_t)u * II + i0 + r) * CC + lane * 2];
            float s = wave_reduce_add(a.x * w1.x + a.y * w1.y);
            if (lane == 0) stv[r] = s + bdv;
        }
        if (t < CC) {
            float acc = bm[t];
            for (int e = 0; e < EE; ++e) acc += user[u * EE + e] * Wm[e * CC + t];
            upv[t] = acc;
        }
    }
    __syncthreads();

    const int l = t & 63;
    const int w = t >> 6;
    const int ln = l & 15;   // A row / D col within tile
    const int g = l >> 4;    // k-group

    // ---- Phase 1: per-lane p (bf16 A-frags in registers) + row sums ----
    bf16x8 a[16];
    float rowsum = 0.0f;
    {
        float s = stv[ln];
#pragma unroll
        for (int t16 = 0; t16 < 16; ++t16) {
            int j = 32 * t16 + 8 * g;
            float4 k0 = *(const float4*)&skv[j];
            float4 k1 = *(const float4*)&skv[j + 4];
            unsigned m0 = *(const unsigned*)&mk[j];
            unsigned m1 = *(const unsigned*)&mk[j + 4];
            float pf[8];
            pf[0] = (m0 & 0x000000FFu) ? __expf(fast_tanh(s + k0.x)) : 0.0f;
            pf[1] = (m0 & 0x0000FF00u) ? __expf(fast_tanh(s + k0.y)) : 0.0f;
            pf[2] = (m0 & 0x00FF0000u) ? __expf(fast_tanh(s + k0.z)) : 0.0f;
            pf[3] = (m0 & 0xFF000000u) ? __expf(fast_tanh(s + k0.w)) : 0.0f;
            pf[4] = (m1 & 0x000000FFu) ? __expf(fast_tanh(s + k1.x)) : 0.0f;
            pf[5] = (m1 & 0x0000FF00u) ? __expf(fast_tanh(s + k1.y)) : 0.0f;
            pf[6] = (m1 & 0x00FF0000u) ? __expf(fast_tanh(s + k1.z)) : 0.0f;
            pf[7] = (m1 & 0xFF000000u) ? __expf(fast_tanh(s + k1.w)) : 0.0f;
            rowsum += pf[0] + pf[1] + pf[2] + pf[3] + pf[4] + pf[5] + pf[6] + pf[7];
            FragU cu;
            cu.u[0] = pack_bf16x2(pf[0], pf[1]);
            cu.u[1] = pack_bf16x2(pf[2], pf[3]);
            cu.u[2] = pack_bf16x2(pf[4], pf[5]);
            cu.u[3] = pack_bf16x2(pf[6], pf[7]);
            a[t16] = cu.v;
        }
    }
    rowsum += __shfl_xor(rowsum, 16, 64);
    rowsum += __shfl_xor(rowsum, 32, 64);
    float dinv = 1.0f / rowsum;
    if (t < 16) dinv_lds[t] = dinv;  // wave 0, rows 0..15 (g==0)

    // ---- Phase 3: write attn = bf16(p) * dinv (unpack frags) ----
    {
        float* abase = out_attn + ((size_t)(u * II + i0 + ln)) * JJ + 8 * g;
#pragma unroll
        for (int t16 = 0; t16 < 16; ++t16) {
            FragU cu; cu.v = a[t16];
            float f0 = __uint_as_float(cu.u[0] << 16) * dinv;
            float f1 = __uint_as_float(cu.u[0] & 0xFFFF0000u) * dinv;
            float f2 = __uint_as_float(cu.u[1] << 16) * dinv;
            float f3 = __uint_as_float(cu.u[1] & 0xFFFF0000u) * dinv;
            float f4 = __uint_as_float(cu.u[2] << 16) * dinv;
            float f5 = __uint_as_float(cu.u[2] & 0xFFFF0000u) * dinv;
            float f6 = __uint_as_float(cu.u[3] << 16) * dinv;
            float f7 = __uint_as_float(cu.u[3] & 0xFFFF0000u) * dinv;
            *(float4*)&abase[32 * t16] = make_float4(f0, f1, f2, f3);
            *(float4*)&abase[32 * t16 + 4] = make_float4(f4, f5, f6, f7);
        }
    }

    // ---- Phase 4: pooled = p @ V via MFMA, V staged transposed bf16 ----
    f32x4 acc0 = {0.f, 0.f, 0.f, 0.f};
    f32x4 acc1 = {0.f, 0.f, 0.f, 0.f};
    const float* Vu = itc + (size_t)u * JJ * CC;
    const int cg = t & 31;  // staging: c lane
    const int jp = t >> 5;  // staging: j-pair base
    const int n0 = w * 32;

    for (int jt = 0; jt < 8; ++jt) {
        int j0 = jt * JT;
        __syncthreads();  // previous tile's MFMA reads complete
#pragma unroll
        for (int it = 0; it < 4; ++it) {
            int jl = 2 * (jp + 8 * it);
            const float* r0 = &Vu[(size_t)(j0 + jl) * CC];
            const float* r1 = r0 + CC;
#pragma unroll
            for (int qq = 0; qq < 4; ++qq) {
                int c = cg + 32 * qq;
                *(unsigned*)&Vt[c][jl] = pack_bf16x2(r0[c], r1[c]);
            }
        }
        __syncthreads();
#pragma unroll
        for (int kk = 0; kk < 2; ++kk) {
            bf16x8 b0 = *(const bf16x8*)&Vt[n0 + ln][32 * kk + 8 * g];
            bf16x8 b1 = *(const bf16x8*)&Vt[n0 + 16 + ln][32 * kk + 8 * g];
            acc0 = __builtin_amdgcn_mfma_f32_16x16x32_bf16(a[2 * jt + kk], b0,
                                                           acc0, 0, 0, 0);
            acc1 = __builtin_amdgcn_mfma_f32_16x16x32_bf16(a[2 * jt + kk], b1,
                                                           acc1, 0, 0, 0);
        }
    }

    // ---- scale by dinv and write pooled to LDS ----
    __syncthreads();
    {
        float4 dv = *(const float4*)&dinv_lds[4 * g];
        float dvr[4] = {dv.x, dv.y, dv.z, dv.w};
#pragma unroll
        for (int r = 0; r < 4; ++r) {
            pool[4 * g + r][n0 + ln] = acc0[r] * dvr[r];
            pool[4 * g + r][n0 + 16 + ln] = acc1[r] * dvr[r];
        }
    }
    __syncthreads();

    // ---- Phase 5: out = relu(u_part + pooled @ W_mlp[E:]) ----
    {
        int tx = t & 15, ty = t >> 4;
        float o[8];
#pragma unroll
        for (int k = 0; k < 8; ++k) o[k] = 0.f;
#pragma unroll 4
        for (int k = 0; k < CC; ++k) {
            float pk = pool[ty][k];
            float4 w0 = *(const float4*)&Wm[(size_t)(EE + k) * CC + tx * 8];
            float4 w1 = *(const float4*)&Wm[(size_t)(EE + k) * CC + tx * 8 + 4];
            o[0] += pk * w0.x; o[1] += pk * w0.y; o[2] += pk * w0.z; o[3] += pk * w0.w;
            o[4] += pk * w1.x; o[5] += pk * w1.y; o[6] += pk * w1.z; o[7] += pk * w1.w;
        }
        float4 up0 = *(const float4*)&upv[tx * 8];
        float4 up1 = *(const float4*)&upv[tx * 8 + 4];
        float4 r0, r1;
        r0.x = fmaxf(o[0] + up0.x, 0.f); r0.y = fmaxf(o[1] + up0.y, 0.f);
        r0.z = fmaxf(o[2] + up0.z, 0.f); r0.w = fmaxf(o[3] + up0.w, 0.f);
        r1.x = fmaxf(o[4] + up1.x, 0.f); r1.y = fmaxf(o[5] + up1.y, 0.f);
        r1.z = fmaxf(o[6] + up1.z, 0.f); r1.w = fmaxf(o[7] + up1.w, 0.f);
        float* ctx = out_ctx + ((size_t)(u * II + i0 + ty)) * CC + tx * 8;
        *(float4*)&ctx[0] = r0;
        *(float4*)&ctx[4] = r1;
    }
}

// ---------------------------------------------------------------------------
extern "C" void kernel_launch(void* const* d_in, const int* in_sizes, int n_in,
                              void* d_out, int out_size, void* d_ws,
                              size_t ws_size, hipStream_t stream) {
    const float* tgt  = (const float*)d_in[0];
    const float* itc  = (const float*)d_in[1];
    const float* user = (const float*)d_in[2];
    const int*   mask = (const int*)d_in[3];
    const float* wd   = (const float*)d_in[4];
    const float* bd   = (const float*)d_in[5];
    const float* Wm   = (const float*)d_in[6];
    const float* bm   = (const float*)d_in[7];
    float* out_ctx  = (float*)d_out;
    float* out_attn = out_ctx + (size_t)UU * II * CC;

    size_t need = (size_t)(UU * II + UU * JJ + UU * CC) * sizeof(float);
    if (ws_size >= need) {
        float* st_g = (float*)d_ws;
        float* sk_g = st_g + UU * II;
        float* up_g = sk_g + UU * JJ;
        int gridA = UU * II / 4 + UU * JJ / 4 + UU * CC / 256;
        precompute_kernel<<<gridA, 256, 0, stream>>>(tgt, itc, user, wd, bd, Wm,
                                                     bm, st_g, sk_g, up_g);
        fused_kernel<true><<<UU * NIB, 256, 0, stream>>>(
            tgt, itc, user, mask, wd, bd, Wm, bm, st_g, sk_g, up_g, out_ctx,
            out_attn);
    } else {
        fused_kernel<false><<<UU * NIB, 256, 0, stream>>>(
            tgt, itc, user, mask, wd, bd, Wm, bm, nullptr, nullptr, nullptr,
            out_ctx, out_attn);
    }
}

// Round 3
// 125.131 us; speedup vs baseline: 2.4738x; 1.2599x over previous
//
#include <hip/hip_runtime.h>

// Problem constants (UserContextAttentionPooler): U=128, I=256, J=512, C=E=128
#define UU 128
#define II 256
#define JJ 512
#define CC 128
#define EE 128
#define IB 16            // i-rows per block
#define NIB 16           // i-tiles per u
#define JT 64            // j per V tile
#define NJT 8            // V tiles per u
#define VTP 72           // (fallback kernel) Vt row stride in shorts

typedef short bf16x8 __attribute__((ext_vector_type(8)));
typedef float f32x4 __attribute__((ext_vector_type(4)));

union FragU { bf16x8 v; unsigned u[4]; };

__device__ __forceinline__ float fast_tanh(float x) {
    float ex = __expf(2.0f * x);
    return 1.0f - 2.0f / (ex + 1.0f);
}

__device__ __forceinline__ unsigned pack_bf16x2(float lo, float hi) {
    unsigned ul = __float_as_uint(lo), uh = __float_as_uint(hi);
    ul = (ul + 0x7FFFu + ((ul >> 16) & 1u)) >> 16;
    uh = (uh + 0x7FFFu + ((uh >> 16) & 1u)) >> 16;
    return ul | (uh << 16);
}

__device__ __forceinline__ float wave_reduce_add(float v) {
#pragma unroll
    for (int k = 32; k >= 1; k >>= 1) v += __shfl_xor(v, k, 64);
    return v;
}

// async 16B/lane global->LDS (linear dest, per-lane source)
__device__ __forceinline__ void gll16(const short* g, short* l) {
    __builtin_amdgcn_global_load_lds(
        (const __attribute__((address_space(1))) unsigned int*)g,
        (__attribute__((address_space(3))) unsigned int*)l, 16, 0, 0);
}

// ---------------------------------------------------------------------------
// Kernel A: precompute s_t (U,I)[+b_dense], s_k (U,J), u_part (U,C)[+b_mlp],
// and Vt_g: per-(u,jt) 16KB tiles of bf16 V^T in swizzled MFMA-B granule order.
// Granule (c,q) at tile byte offset c*128 + 16*(q ^ (c&7)) holds
// V[u][j0+8q+e][c] for e=0..7 (bf16).
// ---------------------------------------------------------------------------
#define ST_BLOCKS (UU * II / 4)   // 8192
#define SK_BLOCKS (UU * JJ / 4)   // 16384
#define UP_BLOCKS (UU * CC / 256) // 64
#define VT_BLOCKS (UU * NJT)      // 1024

__global__ void precompute_kernel(const float* __restrict__ tgt,
                                  const float* __restrict__ itc,
                                  const float* __restrict__ user,
                                  const float* __restrict__ wd,
                                  const float* __restrict__ bd,
                                  const float* __restrict__ Wm,
                                  const float* __restrict__ bm,
                                  float* __restrict__ st_g,
                                  float* __restrict__ sk_g,
                                  float* __restrict__ up_g,
                                  short* __restrict__ vtg) {
    __shared__ float vt_f[JT][CC + 4];
    int b = blockIdx.x;
    int t = threadIdx.x;
    if (b < ST_BLOCKS) {
        int row = b * 4 + (t >> 6);
        int lane = t & 63;
        float2 a = *(const float2*)&tgt[(size_t)row * CC + lane * 2];
        float2 w = *(const float2*)&wd[lane * 2];
        float s = wave_reduce_add(a.x * w.x + a.y * w.y);
        if (lane == 0) st_g[row] = s + bd[0];
    } else if (b < ST_BLOCKS + SK_BLOCKS) {
        int row = (b - ST_BLOCKS) * 4 + (t >> 6);
        int lane = t & 63;
        float2 a = *(const float2*)&itc[(size_t)row * CC + lane * 2];
        float2 w = *(const float2*)&wd[CC + lane * 2];
        float s = wave_reduce_add(a.x * w.x + a.y * w.y);
        if (lane == 0) sk_g[row] = s;
    } else if (b < ST_BLOCKS + SK_BLOCKS + UP_BLOCKS) {
        int idx = (b - ST_BLOCKS - SK_BLOCKS) * 256 + t;
        int u = idx >> 7, c = idx & 127;
        float acc = bm[c];
#pragma unroll 8
        for (int e = 0; e < EE; ++e) acc += user[u * EE + e] * Wm[e * CC + c];
        up_g[idx] = acc;
    } else {
        int vb = b - ST_BLOCKS - SK_BLOCKS - UP_BLOCKS;
        int u = vb >> 3, jt = vb & 7;
        const float* src = itc + ((size_t)u * JJ + jt * JT) * CC;
#pragma unroll
        for (int k = 0; k < 8; ++k) {
            int f = t + 256 * k;
            int row = f >> 5, c4 = (f & 31) * 4;
            *(float4*)&vt_f[row][c4] = *(const float4*)&src[(size_t)row * CC + c4];
        }
        __syncthreads();
        int c = t & 127, qh = t >> 7;
        short* dst = vtg + (size_t)(u * NJT + jt) * 8192;
#pragma unroll
        for (int qq = 0; qq < 4; ++qq) {
            int qg = 4 * qh + qq;
            FragU fu;
#pragma unroll
            for (int pr = 0; pr < 4; ++pr) {
                fu.u[pr] = pack_bf16x2(vt_f[8 * qg + 2 * pr][c],
                                       vt_f[8 * qg + 2 * pr + 1][c]);
            }
            *(bf16x8*)&dst[c * 64 + 8 * (qg ^ (c & 7))] = fu.v;
        }
    }
}

// ---------------------------------------------------------------------------
// Kernel B (main): one block per (u, 16-row i-tile), 512 threads = 8 waves.
// Phase1 dedup'd p compute -> swizzled bf16 LDS + f32 attn write from regs.
// MFMA over 8 double-buffered V tiles staged via global_load_lds (counted
// vmcnt). Wave w owns output cols [16w,16w+16).
// ---------------------------------------------------------------------------
__global__ __launch_bounds__(512, 4) void fused_main(
    const int* __restrict__ mask, const float* __restrict__ Wm,
    const float* __restrict__ st_g, const float* __restrict__ sk_g,
    const float* __restrict__ up_g, const short* __restrict__ vt_g,
    float* __restrict__ out_ctx, float* __restrict__ out_attn) {
    __shared__ short Vt[2][8192];       // 2 x 16KB B-tiles
    __shared__ short ps[8192];          // 16KB p tile (swizzled granules)
    __shared__ float pool[IB][CC + 4];
    __shared__ float dinv_lds[IB];

    int b = blockIdx.x;
    int x = b & 7, qq = b >> 3;
    int u = x + 8 * (qq >> 4);
    int ib = qq & 15;
    int i0 = ib * IB;
    int t = threadIdx.x;
    int w = t >> 6, l = t & 63, ln = l & 15, g = l >> 4;

    const short* vtg_u = vt_g + (size_t)u * (NJT * 8192);

    // issue async stage of tile 0 right away (hides under phase 1)
    {
        const short* g0 = vtg_u + w * 1024 + l * 8;
        gll16(g0, &Vt[0][w * 1024]);
        gll16(g0 + 512, &Vt[0][w * 1024 + 512]);
    }

    // ---- Phase 1: p once per block; 16 elems/thread ----
    int r = t >> 5, seg = t & 31;
    float s = st_g[u * II + i0 + r];
    const float* skb = sk_g + u * JJ;
    const int* mkb = mask + u * JJ;
    float pf[16];
    float dinv;
    {
        float rowsum = 0.f;
#pragma unroll
        for (int h = 0; h < 2; ++h) {
            int jb = 8 * seg + 256 * h;
            float4 k0 = *(const float4*)&skb[jb];
            float4 k1 = *(const float4*)&skb[jb + 4];
            int4 m0 = *(const int4*)&mkb[jb];
            int4 m1 = *(const int4*)&mkb[jb + 4];
            float* pp = pf + 8 * h;
            pp[0] = m0.x ? __expf(fast_tanh(s + k0.x)) : 0.f;
            pp[1] = m0.y ? __expf(fast_tanh(s + k0.y)) : 0.f;
            pp[2] = m0.z ? __expf(fast_tanh(s + k0.z)) : 0.f;
            pp[3] = m0.w ? __expf(fast_tanh(s + k0.w)) : 0.f;
            pp[4] = m1.x ? __expf(fast_tanh(s + k1.x)) : 0.f;
            pp[5] = m1.y ? __expf(fast_tanh(s + k1.y)) : 0.f;
            pp[6] = m1.z ? __expf(fast_tanh(s + k1.z)) : 0.f;
            pp[7] = m1.w ? __expf(fast_tanh(s + k1.w)) : 0.f;
            rowsum += pp[0] + pp[1] + pp[2] + pp[3] + pp[4] + pp[5] + pp[6] + pp[7];
            unsigned q0 = pack_bf16x2(pp[0], pp[1]);
            unsigned q1 = pack_bf16x2(pp[2], pp[3]);
            unsigned q2 = pack_bf16x2(pp[4], pp[5]);
            unsigned q3 = pack_bf16x2(pp[6], pp[7]);
            int gp = (seg + 32 * h) ^ (r & 7);
            *(uint4*)((char*)ps + r * 1024 + 16 * gp) = make_uint4(q0, q1, q2, q3);
        }
#pragma unroll
        for (int k = 1; k <= 16; k <<= 1) rowsum += __shfl_xor(rowsum, k, 64);
        dinv = 1.0f / rowsum;
        if (seg == 0) dinv_lds[r] = dinv;
    }

    // ---- Phase 2: attn write (dedup'd, f32 from regs) ----
    {
        float* ab = out_attn + ((size_t)(u * II + i0 + r)) * JJ;
#pragma unroll
        for (int h = 0; h < 2; ++h) {
            int jb = 8 * seg + 256 * h;
            const float* pp = pf + 8 * h;
            *(float4*)&ab[jb] =
                make_float4(pp[0] * dinv, pp[1] * dinv, pp[2] * dinv, pp[3] * dinv);
            *(float4*)&ab[jb + 4] =
                make_float4(pp[4] * dinv, pp[5] * dinv, pp[6] * dinv, pp[7] * dinv);
        }
    }

    // ---- Phase 3: MFMA over 8 tiles, double-buffered, counted vmcnt ----
    f32x4 acc = {0.f, 0.f, 0.f, 0.f};
    const int n0 = 16 * w;
#pragma unroll
    for (int jt = 0; jt < NJT; ++jt) {
        int buf = jt & 1;
        if (jt < NJT - 1) {
            const short* gn = vtg_u + (jt + 1) * 8192 + w * 1024 + l * 8;
            gll16(gn, &Vt[buf ^ 1][w * 1024]);
            gll16(gn + 512, &Vt[buf ^ 1][w * 1024 + 512]);
            asm volatile("s_waitcnt vmcnt(2) lgkmcnt(0)" ::: "memory");
        } else {
            asm volatile("s_waitcnt vmcnt(0) lgkmcnt(0)" ::: "memory");
        }
        __builtin_amdgcn_s_barrier();
#pragma unroll
        for (int kk = 0; kk < 2; ++kk) {
            bf16x8 af = *(const bf16x8*)((const char*)ps + ln * 1024 +
                                         16 * ((8 * jt + 4 * kk + g) ^ (ln & 7)));
            bf16x8 bfr = *(const bf16x8*)((const char*)&Vt[buf][0] +
                                          (n0 + ln) * 128 +
                                          16 * ((4 * kk + g) ^ (ln & 7)));
            acc = __builtin_amdgcn_mfma_f32_16x16x32_bf16(af, bfr, acc, 0, 0, 0);
        }
        asm volatile("s_waitcnt lgkmcnt(0)" ::: "memory");
        __builtin_amdgcn_s_barrier();
    }

    // ---- Phase 4: scale by dinv, pooled -> LDS ----
#pragma unroll
    for (int ri = 0; ri < 4; ++ri)
        pool[4 * g + ri][n0 + ln] = acc[ri] * dinv_lds[4 * g + ri];
    __syncthreads();

    // ---- Phase 5: out = relu(u_part + pooled @ W_mlp[E:]) ----
    {
        int tx = t & 31, ty = t >> 5;
        float o0 = 0.f, o1 = 0.f, o2 = 0.f, o3 = 0.f;
#pragma unroll 8
        for (int k = 0; k < CC; ++k) {
            float pk2 = pool[ty][k];
            float4 wv = *(const float4*)&Wm[(size_t)(EE + k) * CC + 4 * tx];
            o0 += pk2 * wv.x; o1 += pk2 * wv.y; o2 += pk2 * wv.z; o3 += pk2 * wv.w;
        }
        float4 up = *(const float4*)&up_g[u * CC + 4 * tx];
        float4 rr;
        rr.x = fmaxf(o0 + up.x, 0.f);
        rr.y = fmaxf(o1 + up.y, 0.f);
        rr.z = fmaxf(o2 + up.z, 0.f);
        rr.w = fmaxf(o3 + up.w, 0.f);
        *(float4*)&out_ctx[((size_t)(u * II + i0 + ty)) * CC + 4 * tx] = rr;
    }
}

// ---------------------------------------------------------------------------
// Fallback (ws too small): round-2 validated self-contained kernel.
// ---------------------------------------------------------------------------
__global__ __launch_bounds__(256, 3) void fused_fallback(
    const float* __restrict__ tgt, const float* __restrict__ itc,
    const float* __restrict__ user, const int* __restrict__ mask,
    const float* __restrict__ wd, const float* __restrict__ bd,
    const float* __restrict__ Wm, const float* __restrict__ bm,
    float* __restrict__ out_ctx, float* __restrict__ out_attn) {
    __shared__ __align__(16) short Vt[CC][VTP];
    __shared__ __align__(16) float pool[IB][CC + 4];
    __shared__ __align__(16) float skv[JJ];
    __shared__ __align__(16) float stv[IB];
    __shared__ __align__(16) float upv[CC];
    __shared__ __align__(16) float dinv_lds[IB];
    __shared__ unsigned char mk[JJ];

    int b = blockIdx.x;
    int x = b & 7, q = b >> 3;
    int u = x + 8 * (q >> 4);
    int ib = q & 15;
    int i0 = ib * IB;
    int t = threadIdx.x;

    mk[t] = (unsigned char)(mask[u * JJ + t] != 0);
    mk[t + 256] = (unsigned char)(mask[u * JJ + t + 256] != 0);

    {
        int lane = t & 63, w4 = t >> 6;
        float2 w2 = *(const float2*)&wd[CC + lane * 2];
        for (int r = w4; r < JJ; r += 4) {
            float2 a = *(const float2*)&itc[((size_t)u * JJ + r) * CC + lane * 2];
            float s = wave_reduce_add(a.x * w2.x + a.y * w2.y);
            if (lane == 0) skv[r] = s;
        }
        float2 w1 = *(const float2*)&wd[lane * 2];
        float bdv = bd[0];
        for (int r = w4; r < IB; r += 4) {
            float2 a = *(const float2*)&tgt[((size_t)u * II + i0 + r) * CC + lane * 2];
            float s = wave_reduce_add(a.x * w1.x + a.y * w1.y);
            if (lane == 0) stv[r] = s + bdv;
        }
        if (t < CC) {
            float acc = bm[t];
            for (int e = 0; e < EE; ++e) acc += user[u * EE + e] * Wm[e * CC + t];
            upv[t] = acc;
        }
    }
    __syncthreads();

    const int l = t & 63;
    const int w = t >> 6;
    const int ln = l & 15;
    const int g = l >> 4;

    bf16x8 a[16];
    float rowsum = 0.0f;
    {
        float s = stv[ln];
#pragma unroll
        for (int t16 = 0; t16 < 16; ++t16) {
            int j = 32 * t16 + 8 * g;
            float4 k0 = *(const float4*)&skv[j];
            float4 k1 = *(const float4*)&skv[j + 4];
            unsigned m0 = *(const unsigned*)&mk[j];
            unsigned m1 = *(const unsigned*)&mk[j + 4];
            float pf[8];
            pf[0] = (m0 & 0x000000FFu) ? __expf(fast_tanh(s + k0.x)) : 0.0f;
            pf[1] = (m0 & 0x0000FF00u) ? __expf(fast_tanh(s + k0.y)) : 0.0f;
            pf[2] = (m0 & 0x00FF0000u) ? __expf(fast_tanh(s + k0.z)) : 0.0f;
            pf[3] = (m0 & 0xFF000000u) ? __expf(fast_tanh(s + k0.w)) : 0.0f;
            pf[4] = (m1 & 0x000000FFu) ? __expf(fast_tanh(s + k1.x)) : 0.0f;
            pf[5] = (m1 & 0x0000FF00u) ? __expf(fast_tanh(s + k1.y)) : 0.0f;
            pf[6] = (m1 & 0x00FF0000u) ? __expf(fast_tanh(s + k1.z)) : 0.0f;
            pf[7] = (m1 & 0xFF000000u) ? __expf(fast_tanh(s + k1.w)) : 0.0f;
            rowsum += pf[0] + pf[1] + pf[2] + pf[3] + pf[4] + pf[5] + pf[6] + pf[7];
            FragU cu;
            cu.u[0] = pack_bf16x2(pf[0], pf[1]);
            cu.u[1] = pack_bf16x2(pf[2], pf[3]);
            cu.u[2] = pack_bf16x2(pf[4], pf[5]);
            cu.u[3] = pack_bf16x2(pf[6], pf[7]);
            a[t16] = cu.v;
        }
    }
    rowsum += __shfl_xor(rowsum, 16, 64);
    rowsum += __shfl_xor(rowsum, 32, 64);
    float dinv = 1.0f / rowsum;
    if (t < 16) dinv_lds[t] = dinv;

    {
        float* abase = out_attn + ((size_t)(u * II + i0 + ln)) * JJ + 8 * g;
#pragma unroll
        for (int t16 = 0; t16 < 16; ++t16) {
            FragU cu; cu.v = a[t16];
            float f0 = __uint_as_float(cu.u[0] << 16) * dinv;
            float f1 = __uint_as_float(cu.u[0] & 0xFFFF0000u) * dinv;
            float f2 = __uint_as_float(cu.u[1] << 16) * dinv;
            float f3 = __uint_as_float(cu.u[1] & 0xFFFF0000u) * dinv;
            float f4 = __uint_as_float(cu.u[2] << 16) * dinv;
            float f5 = __uint_as_float(cu.u[2] & 0xFFFF0000u) * dinv;
            float f6 = __uint_as_float(cu.u[3] << 16) * dinv;
            float f7 = __uint_as_float(cu.u[3] & 0xFFFF0000u) * dinv;
            *(float4*)&abase[32 * t16] = make_float4(f0, f1, f2, f3);
            *(float4*)&abase[32 * t16 + 4] = make_float4(f4, f5, f6, f7);
        }
    }

    f32x4 acc0 = {0.f, 0.f, 0.f, 0.f};
    f32x4 acc1 = {0.f, 0.f, 0.f, 0.f};
    const float* Vu = itc + (size_t)u * JJ * CC;
    const int cg = t & 31;
    const int jp = t >> 5;
    const int n0 = w * 32;

    for (int jt = 0; jt < 8; ++jt) {
        int j0 = jt * JT;
        __syncthreads();
#pragma unroll
        for (int it = 0; it < 4; ++it) {
            int jl = 2 * (jp + 8 * it);
            const float* r0 = &Vu[(size_t)(j0 + jl) * CC];
            const float* r1 = r0 + CC;
#pragma unroll
            for (int qv = 0; qv < 4; ++qv) {
                int c = cg + 32 * qv;
                *(unsigned*)&Vt[c][jl] = pack_bf16x2(r0[c], r1[c]);
            }
        }
        __syncthreads();
#pragma unroll
        for (int kk = 0; kk < 2; ++kk) {
            bf16x8 b0 = *(const bf16x8*)&Vt[n0 + ln][32 * kk + 8 * g];
            bf16x8 b1 = *(const bf16x8*)&Vt[n0 + 16 + ln][32 * kk + 8 * g];
            acc0 = __builtin_amdgcn_mfma_f32_16x16x32_bf16(a[2 * jt + kk], b0,
                                                           acc0, 0, 0, 0);
            acc1 = __builtin_amdgcn_mfma_f32_16x16x32_bf16(a[2 * jt + kk], b1,
                                                           acc1, 0, 0, 0);
        }
    }

    __syncthreads();
    {
        float4 dv = *(const float4*)&dinv_lds[4 * g];
        float dvr[4] = {dv.x, dv.y, dv.z, dv.w};
#pragma unroll
        for (int r = 0; r < 4; ++r) {
            pool[4 * g + r][n0 + ln] = acc0[r] * dvr[r];
            pool[4 * g + r][n0 + 16 + ln] = acc1[r] * dvr[r];
        }
    }
    __syncthreads();

    {
        int tx = t & 15, ty = t >> 4;
        float o[8];
#pragma unroll
        for (int k = 0; k < 8; ++k) o[k] = 0.f;
#pragma unroll 4
        for (int k = 0; k < CC; ++k) {
            float pk = pool[ty][k];
            float4 w0 = *(const float4*)&Wm[(size_t)(EE + k) * CC + tx * 8];
            float4 w1 = *(const float4*)&Wm[(size_t)(EE + k) * CC + tx * 8 + 4];
            o[0] += pk * w0.x; o[1] += pk * w0.y; o[2] += pk * w0.z; o[3] += pk * w0.w;
            o[4] += pk * w1.x; o[5] += pk * w1.y; o[6] += pk * w1.z; o[7] += pk * w1.w;
        }
        float4 up0 = *(const float4*)&upv[tx * 8];
        float4 up1 = *(const float4*)&upv[tx * 8 + 4];
        float4 r0, r1;
        r0.x = fmaxf(o[0] + up0.x, 0.f); r0.y = fmaxf(o[1] + up0.y, 0.f);
        r0.z = fmaxf(o[2] + up0.z, 0.f); r0.w = fmaxf(o[3] + up0.w, 0.f);
        r1.x = fmaxf(o[4] + up1.x, 0.f); r1.y = fmaxf(o[5] + up1.y, 0.f);
        r1.z = fmaxf(o[6] + up1.z, 0.f); r1.w = fmaxf(o[7] + up1.w, 0.f);
        float* ctx = out_ctx + ((size_t)(u * II + i0 + ty)) * CC + tx * 8;
        *(float4*)&ctx[0] = r0;
        *(float4*)&ctx[4] = r1;
    }
}

// ---------------------------------------------------------------------------
extern "C" void kernel_launch(void* const* d_in, const int* in_sizes, int n_in,
                              void* d_out, int out_size, void* d_ws,
                              size_t ws_size, hipStream_t stream) {
    const float* tgt  = (const float*)d_in[0];
    const float* itc  = (const float*)d_in[1];
    const float* user = (const float*)d_in[2];
    const int*   mask = (const int*)d_in[3];
    const float* wd   = (const float*)d_in[4];
    const float* bd   = (const float*)d_in[5];
    const float* Wm   = (const float*)d_in[6];
    const float* bm   = (const float*)d_in[7];
    float* out_ctx  = (float*)d_out;
    float* out_attn = out_ctx + (size_t)UU * II * CC;

    size_t scalars = (size_t)(UU * II + UU * JJ + UU * CC) * sizeof(float);
    size_t need = scalars + (size_t)UU * NJT * 8192 * sizeof(short);
    if (ws_size >= need) {
        float* st_g = (float*)d_ws;
        float* sk_g = st_g + UU * II;
        float* up_g = sk_g + UU * JJ;
        short* vt_g = (short*)((char*)d_ws + scalars);
        int gridA = ST_BLOCKS + SK_BLOCKS + UP_BLOCKS + VT_BLOCKS;
        precompute_kernel<<<gridA, 256, 0, stream>>>(tgt, itc, user, wd, bd, Wm,
                                                     bm, st_g, sk_g, up_g, vt_g);
        fused_main<<<UU * NIB, 512, 0, stream>>>(mask, Wm, st_g, sk_g, up_g,
                                                 vt_g, out_ctx, out_attn);
    } else {
        fused_fallback<<<UU * NIB, 256, 0, stream>>>(
            tgt, itc, user, mask, wd, bd, Wm, bm, out_ctx, out_attn);
    }
}

// Round 4
// 111.774 us; speedup vs baseline: 2.7695x; 1.1195x over previous
//
#include <hip/hip_runtime.h>

// Problem constants (UserContextAttentionPooler): U=128, I=256, J=512, C=E=128
#define UU 128
#define II 256
#define JJ 512
#define CC 128
#define EE 128
#define IB 16            // i-rows per block
#define NIB 16           // i-tiles per u
#define JT 64            // j per V tile
#define NJT 8            // V tiles per u
#define VTP 72           // (fallback kernel) Vt row stride in shorts

typedef short bf16x8 __attribute__((ext_vector_type(8)));
typedef float f32x4 __attribute__((ext_vector_type(4)));

union FragU { bf16x8 v; unsigned u[4]; };

__device__ __forceinline__ float fast_tanh(float x) {
    float ex = __expf(2.0f * x);
    return 1.0f - 2.0f / (ex + 1.0f);
}

__device__ __forceinline__ unsigned pack_bf16x2(float lo, float hi) {
    unsigned ul = __float_as_uint(lo), uh = __float_as_uint(hi);
    ul = (ul + 0x7FFFu + ((ul >> 16) & 1u)) >> 16;
    uh = (uh + 0x7FFFu + ((uh >> 16) & 1u)) >> 16;
    return ul | (uh << 16);
}

__device__ __forceinline__ float wave_reduce_add(float v) {
#pragma unroll
    for (int k = 32; k >= 1; k >>= 1) v += __shfl_xor(v, k, 64);
    return v;
}

// ---------------------------------------------------------------------------
// Kernel A: precompute s_t (U,I)[+b_dense], u_part (U,C)[+b_mlp], and
// Vt_g tiles; s_k is computed inside the Vt pass (itc read once there).
// Vt tile (u,jt) layout, short index: kk*4096 + c*32 + (j_local&31),
// kk = j_local>>5 — so a wave's B-frag load (rows c..c+15, one kk-half,
// lanes (ln,g) at (c+ln)*32 + 8g) is 1KB fully contiguous.
// ---------------------------------------------------------------------------
#define ST_BLOCKS (UU * II / 4)   // 8192
#define UP_BLOCKS (UU * CC / 256) // 64
#define VT_BLOCKS (UU * NJT)      // 1024

__global__ void precompute_kernel(const float* __restrict__ tgt,
                                  const float* __restrict__ itc,
                                  const float* __restrict__ user,
                                  const float* __restrict__ wd,
                                  const float* __restrict__ bd,
                                  const float* __restrict__ Wm,
                                  const float* __restrict__ bm,
                                  float* __restrict__ st_g,
                                  float* __restrict__ sk_g,
                                  float* __restrict__ up_g,
                                  short* __restrict__ vtg) {
    __shared__ float vt_f[JT][CC + 4];
    int b = blockIdx.x;
    int t = threadIdx.x;
    if (b < ST_BLOCKS) {
        int row = b * 4 + (t >> 6);
        int lane = t & 63;
        float2 a = *(const float2*)&tgt[(size_t)row * CC + lane * 2];
        float2 w = *(const float2*)&wd[lane * 2];
        float s = wave_reduce_add(a.x * w.x + a.y * w.y);
        if (lane == 0) st_g[row] = s + bd[0];
    } else if (b < ST_BLOCKS + UP_BLOCKS) {
        int idx = (b - ST_BLOCKS) * 256 + t;
        int u = idx >> 7, c = idx & 127;
        float acc = bm[c];
#pragma unroll 8
        for (int e = 0; e < EE; ++e) acc += user[u * EE + e] * Wm[e * CC + c];
        up_g[idx] = acc;
    } else {
        int vb = b - ST_BLOCKS - UP_BLOCKS;
        int u = vb >> 3, jt = vb & 7;
        const float* src = itc + ((size_t)u * JJ + jt * JT) * CC;
#pragma unroll
        for (int k = 0; k < 8; ++k) {
            int f = t + 256 * k;
            int row = f >> 5, c4 = (f & 31) * 4;
            *(float4*)&vt_f[row][c4] = *(const float4*)&src[(size_t)row * CC + c4];
        }
        __syncthreads();
        // s_k for these 64 rows (4 threads per row, 32 c each)
        {
            int r = t >> 2, q4 = t & 3;
            float s = 0.f;
#pragma unroll
            for (int cc = 0; cc < 32; cc += 4) {
                float4 a = *(const float4*)&vt_f[r][q4 * 32 + cc];
                float4 w = *(const float4*)&wd[CC + q4 * 32 + cc];
                s += a.x * w.x + a.y * w.y + a.z * w.z + a.w * w.w;
            }
            s += __shfl_xor(s, 1, 64);
            s += __shfl_xor(s, 2, 64);
            if (q4 == 0) sk_g[u * JJ + jt * JT + r] = s;
        }
        // pack transposed bf16 tile: [kk][c][j&31]
        {
            int c = t & 127, half = t >> 7;
            unsigned* dst = (unsigned*)(vtg + (size_t)(u * NJT + jt) * 8192) +
                            half * 2048 + c * 16;
#pragma unroll
            for (int m = 0; m < 16; ++m) {
                dst[m] = pack_bf16x2(vt_f[32 * half + 2 * m][c],
                                     vt_f[32 * half + 2 * m + 1][c]);
            }
        }
    }
}

// ---------------------------------------------------------------------------
// Kernel B (main): one block per (u, 16-row i-tile), 256 threads = 4 waves.
// Phase1 dedup'd p -> swizzled bf16 LDS + f32 attn write from regs.
// Barrier-free K loop: A-frags via ds_read_b128, B-frags DIRECT from global
// (L2-resident vt_g, coalesced 1KB/wave loads). Wave w owns cols [32w,32w+32).
// ---------------------------------------------------------------------------
__global__ __launch_bounds__(256, 4) void fused_main(
    const int* __restrict__ mask, const float* __restrict__ Wm,
    const float* __restrict__ st_g, const float* __restrict__ sk_g,
    const float* __restrict__ up_g, const short* __restrict__ vt_g,
    float* __restrict__ out_ctx, float* __restrict__ out_attn) {
    __shared__ __align__(16) short ps[8192];   // 16KB p tile (swizzled granules)
    __shared__ __align__(16) float pool[IB][CC + 4];
    __shared__ float dinv_lds[IB];

    int b = blockIdx.x;
    int x = b & 7, qq = b >> 3;
    int u = x + 8 * (qq >> 4);     // 16 blocks of a given u -> same XCD
    int ib = qq & 15;
    int i0 = ib * IB;
    int t = threadIdx.x;
    int w = t >> 6, l = t & 63, ln = l & 15, g = l >> 4;

    // ---- Phase 1: p once per block; 32 elems/thread (row r, seg s4) ----
    int r = t >> 4, s4 = t & 15;
    float s = st_g[u * II + i0 + r];
    const float* skb = sk_g + u * JJ;
    const int* mkb = mask + u * JJ;
    float pf[32];
    float rowsum = 0.f;
#pragma unroll
    for (int h = 0; h < 4; ++h) {
        int jb = 8 * (s4 + 16 * h);
        float4 k0 = *(const float4*)&skb[jb];
        float4 k1 = *(const float4*)&skb[jb + 4];
        int4 m0 = *(const int4*)&mkb[jb];
        int4 m1 = *(const int4*)&mkb[jb + 4];
        float* pp = pf + 8 * h;
        pp[0] = m0.x ? __expf(fast_tanh(s + k0.x)) : 0.f;
        pp[1] = m0.y ? __expf(fast_tanh(s + k0.y)) : 0.f;
        pp[2] = m0.z ? __expf(fast_tanh(s + k0.z)) : 0.f;
        pp[3] = m0.w ? __expf(fast_tanh(s + k0.w)) : 0.f;
        pp[4] = m1.x ? __expf(fast_tanh(s + k1.x)) : 0.f;
        pp[5] = m1.y ? __expf(fast_tanh(s + k1.y)) : 0.f;
        pp[6] = m1.z ? __expf(fast_tanh(s + k1.z)) : 0.f;
        pp[7] = m1.w ? __expf(fast_tanh(s + k1.w)) : 0.f;
        rowsum += pp[0] + pp[1] + pp[2] + pp[3] + pp[4] + pp[5] + pp[6] + pp[7];
        unsigned q0 = pack_bf16x2(pp[0], pp[1]);
        unsigned q1 = pack_bf16x2(pp[2], pp[3]);
        unsigned q2 = pack_bf16x2(pp[4], pp[5]);
        unsigned q3 = pack_bf16x2(pp[6], pp[7]);
        int gp = (s4 + 16 * h) ^ (r & 7);
        *(uint4*)((char*)ps + r * 1024 + 16 * gp) = make_uint4(q0, q1, q2, q3);
    }
    rowsum += __shfl_xor(rowsum, 1, 64);
    rowsum += __shfl_xor(rowsum, 2, 64);
    rowsum += __shfl_xor(rowsum, 4, 64);
    rowsum += __shfl_xor(rowsum, 8, 64);
    float dinv = 1.0f / rowsum;
    if (s4 == 0) dinv_lds[r] = dinv;

    // ---- Phase 2: attn write (dedup'd, f32 from regs) ----
    {
        float* ab = out_attn + ((size_t)(u * II + i0 + r)) * JJ;
#pragma unroll
        for (int h = 0; h < 4; ++h) {
            int jb = 8 * (s4 + 16 * h);
            const float* pp = pf + 8 * h;
            *(float4*)&ab[jb] =
                make_float4(pp[0] * dinv, pp[1] * dinv, pp[2] * dinv, pp[3] * dinv);
            *(float4*)&ab[jb + 4] =
                make_float4(pp[4] * dinv, pp[5] * dinv, pp[6] * dinv, pp[7] * dinv);
        }
    }
    __syncthreads();

    // ---- Phase 3: barrier-free MFMA K loop, B direct from global ----
    f32x4 acc0 = {0.f, 0.f, 0.f, 0.f};
    f32x4 acc1 = {0.f, 0.f, 0.f, 0.f};
    const short* b_base =
        vt_g + (size_t)u * (NJT * 8192) + (32 * w + ln) * 32 + 8 * g;
#pragma unroll
    for (int jt = 0; jt < NJT; ++jt) {
#pragma unroll
        for (int kk = 0; kk < 2; ++kk) {
            int step = 2 * jt + kk;
            bf16x8 af = *(const bf16x8*)((const char*)ps + ln * 1024 +
                                         16 * ((4 * step + g) ^ (ln & 7)));
            bf16x8 b0 = *(const bf16x8*)&b_base[jt * 8192 + kk * 4096];
            bf16x8 b1 = *(const bf16x8*)&b_base[jt * 8192 + kk * 4096 + 512];
            acc0 = __builtin_amdgcn_mfma_f32_16x16x32_bf16(af, b0, acc0, 0, 0, 0);
            acc1 = __builtin_amdgcn_mfma_f32_16x16x32_bf16(af, b1, acc1, 0, 0, 0);
        }
    }

    // ---- Phase 4: scale by dinv, pooled -> LDS ----
#pragma unroll
    for (int ri = 0; ri < 4; ++ri) {
        float dv = dinv_lds[4 * g + ri];
        pool[4 * g + ri][32 * w + ln] = acc0[ri] * dv;
        pool[4 * g + ri][32 * w + 16 + ln] = acc1[ri] * dv;
    }
    __syncthreads();

    // ---- Phase 5: out = relu(u_part + pooled @ W_mlp[E:]) ----
    {
        int tx = t & 15, ty = t >> 4;
        float o[8];
#pragma unroll
        for (int k = 0; k < 8; ++k) o[k] = 0.f;
#pragma unroll 4
        for (int k = 0; k < CC; ++k) {
            float pk = pool[ty][k];
            float4 w0 = *(const float4*)&Wm[(size_t)(EE + k) * CC + tx * 8];
            float4 w1 = *(const float4*)&Wm[(size_t)(EE + k) * CC + tx * 8 + 4];
            o[0] += pk * w0.x; o[1] += pk * w0.y; o[2] += pk * w0.z; o[3] += pk * w0.w;
            o[4] += pk * w1.x; o[5] += pk * w1.y; o[6] += pk * w1.z; o[7] += pk * w1.w;
        }
        float4 up0 = *(const float4*)&up_g[u * CC + tx * 8];
        float4 up1 = *(const float4*)&up_g[u * CC + tx * 8 + 4];
        float4 r0, r1;
        r0.x = fmaxf(o[0] + up0.x, 0.f); r0.y = fmaxf(o[1] + up0.y, 0.f);
        r0.z = fmaxf(o[2] + up0.z, 0.f); r0.w = fmaxf(o[3] + up0.w, 0.f);
        r1.x = fmaxf(o[4] + up1.x, 0.f); r1.y = fmaxf(o[5] + up1.y, 0.f);
        r1.z = fmaxf(o[6] + up1.z, 0.f); r1.w = fmaxf(o[7] + up1.w, 0.f);
        float* ctx = out_ctx + ((size_t)(u * II + i0 + ty)) * CC + tx * 8;
        *(float4*)&ctx[0] = r0;
        *(float4*)&ctx[4] = r1;
    }
}

// ---------------------------------------------------------------------------
// Fallback (ws too small): round-2 validated self-contained kernel.
// ---------------------------------------------------------------------------
__global__ __launch_bounds__(256, 3) void fused_fallback(
    const float* __restrict__ tgt, const float* __restrict__ itc,
    const float* __restrict__ user, const int* __restrict__ mask,
    const float* __restrict__ wd, const float* __restrict__ bd,
    const float* __restrict__ Wm, const float* __restrict__ bm,
    float* __restrict__ out_ctx, float* __restrict__ out_attn) {
    __shared__ __align__(16) short Vt[CC][VTP];
    __shared__ __align__(16) float pool[IB][CC + 4];
    __shared__ __align__(16) float skv[JJ];
    __shared__ __align__(16) float stv[IB];
    __shared__ __align__(16) float upv[CC];
    __shared__ __align__(16) float dinv_lds[IB];
    __shared__ unsigned char mk[JJ];

    int b = blockIdx.x;
    int x = b & 7, q = b >> 3;
    int u = x + 8 * (q >> 4);
    int ib = q & 15;
    int i0 = ib * IB;
    int t = threadIdx.x;

    mk[t] = (unsigned char)(mask[u * JJ + t] != 0);
    mk[t + 256] = (unsigned char)(mask[u * JJ + t + 256] != 0);

    {
        int lane = t & 63, w4 = t >> 6;
        float2 w2 = *(const float2*)&wd[CC + lane * 2];
        for (int r = w4; r < JJ; r += 4) {
            float2 a = *(const float2*)&itc[((size_t)u * JJ + r) * CC + lane * 2];
            float s = wave_reduce_add(a.x * w2.x + a.y * w2.y);
            if (lane == 0) skv[r] = s;
        }
        float2 w1 = *(const float2*)&wd[lane * 2];
        float bdv = bd[0];
        for (int r = w4; r < IB; r += 4) {
            float2 a = *(const float2*)&tgt[((size_t)u * II + i0 + r) * CC + lane * 2];
            float s = wave_reduce_add(a.x * w1.x + a.y * w1.y);
            if (lane == 0) stv[r] = s + bdv;
        }
        if (t < CC) {
            float acc = bm[t];
            for (int e = 0; e < EE; ++e) acc += user[u * EE + e] * Wm[e * CC + t];
            upv[t] = acc;
        }
    }
    __syncthreads();

    const int l = t & 63;
    const int w = t >> 6;
    const int ln = l & 15;
    const int g = l >> 4;

    bf16x8 a[16];
    float rowsum = 0.0f;
    {
        float s = stv[ln];
#pragma unroll
        for (int t16 = 0; t16 < 16; ++t16) {
            int j = 32 * t16 + 8 * g;
            float4 k0 = *(const float4*)&skv[j];
            float4 k1 = *(const float4*)&skv[j + 4];
            unsigned m0 = *(const unsigned*)&mk[j];
            unsigned m1 = *(const unsigned*)&mk[j + 4];
            float pf[8];
            pf[0] = (m0 & 0x000000FFu) ? __expf(fast_tanh(s + k0.x)) : 0.0f;
            pf[1] = (m0 & 0x0000FF00u) ? __expf(fast_tanh(s + k0.y)) : 0.0f;
            pf[2] = (m0 & 0x00FF0000u) ? __expf(fast_tanh(s + k0.z)) : 0.0f;
            pf[3] = (m0 & 0xFF000000u) ? __expf(fast_tanh(s + k0.w)) : 0.0f;
            pf[4] = (m1 & 0x000000FFu) ? __expf(fast_tanh(s + k1.x)) : 0.0f;
            pf[5] = (m1 & 0x0000FF00u) ? __expf(fast_tanh(s + k1.y)) : 0.0f;
            pf[6] = (m1 & 0x00FF0000u) ? __expf(fast_tanh(s + k1.z)) : 0.0f;
            pf[7] = (m1 & 0xFF000000u) ? __expf(fast_tanh(s + k1.w)) : 0.0f;
            rowsum += pf[0] + pf[1] + pf[2] + pf[3] + pf[4] + pf[5] + pf[6] + pf[7];
            FragU cu;
            cu.u[0] = pack_bf16x2(pf[0], pf[1]);
            cu.u[1] = pack_bf16x2(pf[2], pf[3]);
            cu.u[2] = pack_bf16x2(pf[4], pf[5]);
            cu.u[3] = pack_bf16x2(pf[6], pf[7]);
            a[t16] = cu.v;
        }
    }
    rowsum += __shfl_xor(rowsum, 16, 64);
    rowsum += __shfl_xor(rowsum, 32, 64);
    float dinv = 1.0f / rowsum;
    if (t < 16) dinv_lds[t] = dinv;

    {
        float* abase = out_attn + ((size_t)(u * II + i0 + ln)) * JJ + 8 * g;
#pragma unroll
        for (int t16 = 0; t16 < 16; ++t16) {
            FragU cu; cu.v = a[t16];
            float f0 = __uint_as_float(cu.u[0] << 16) * dinv;
            float f1 = __uint_as_float(cu.u[0] & 0xFFFF0000u) * dinv;
            float f2 = __uint_as_float(cu.u[1] << 16) * dinv;
            float f3 = __uint_as_float(cu.u[1] & 0xFFFF0000u) * dinv;
            float f4 = __uint_as_float(cu.u[2] << 16) * dinv;
            float f5 = __uint_as_float(cu.u[2] & 0xFFFF0000u) * dinv;
            float f6 = __uint_as_float(cu.u[3] << 16) * dinv;
            float f7 = __uint_as_float(cu.u[3] & 0xFFFF0000u) * dinv;
            *(float4*)&abase[32 * t16] = make_float4(f0, f1, f2, f3);
            *(float4*)&abase[32 * t16 + 4] = make_float4(f4, f5, f6, f7);
        }
    }

    f32x4 acc0 = {0.f, 0.f, 0.f, 0.f};
    f32x4 acc1 = {0.f, 0.f, 0.f, 0.f};
    const float* Vu = itc + (size_t)u * JJ * CC;
    const int cg = t & 31;
    const int jp = t >> 5;
    const int n0 = w * 32;

    for (int jt = 0; jt < 8; ++jt) {
        int j0 = jt * JT;
        __syncthreads();
#pragma unroll
        for (int it = 0; it < 4; ++it) {
            int jl = 2 * (jp + 8 * it);
            const float* r0 = &Vu[(size_t)(j0 + jl) * CC];
            const float* r1 = r0 + CC;
#pragma unroll
            for (int qv = 0; qv < 4; ++qv) {
                int c = cg + 32 * qv;
                *(unsigned*)&Vt[c][jl] = pack_bf16x2(r0[c], r1[c]);
            }
        }
        __syncthreads();
#pragma unroll
        for (int kk = 0; kk < 2; ++kk) {
            bf16x8 b0 = *(const bf16x8*)&Vt[n0 + ln][32 * kk + 8 * g];
            bf16x8 b1 = *(const bf16x8*)&Vt[n0 + 16 + ln][32 * kk + 8 * g];
            acc0 = __builtin_amdgcn_mfma_f32_16x16x32_bf16(a[2 * jt + kk], b0,
                                                           acc0, 0, 0, 0);
            acc1 = __builtin_amdgcn_mfma_f32_16x16x32_bf16(a[2 * jt + kk], b1,
                                                           acc1, 0, 0, 0);
        }
    }

    __syncthreads();
    {
        float4 dv = *(const float4*)&dinv_lds[4 * g];
        float dvr[4] = {dv.x, dv.y, dv.z, dv.w};
#pragma unroll
        for (int r = 0; r < 4; ++r) {
            pool[4 * g + r][n0 + ln] = acc0[r] * dvr[r];
            pool[4 * g + r][n0 + 16 + ln] = acc1[r] * dvr[r];
        }
    }
    __syncthreads();

    {
        int tx = t & 15, ty = t >> 4;
        float o[8];
#pragma unroll
        for (int k = 0; k < 8; ++k) o[k] = 0.f;
#pragma unroll 4
        for (int k = 0; k < CC; ++k) {
            float pk = pool[ty][k];
            float4 w0 = *(const float4*)&Wm[(size_t)(EE + k) * CC + tx * 8];
            float4 w1 = *(const float4*)&Wm[(size_t)(EE + k) * CC + tx * 8 + 4];
            o[0] += pk * w0.x; o[1] += pk * w0.y; o[2] += pk * w0.z; o[3] += pk * w0.w;
            o[4] += pk * w1.x; o[5] += pk * w1.y; o[6] += pk * w1.z; o[7] += pk * w1.w;
        }
        float4 up0 = *(const float4*)&upv[tx * 8];
        float4 up1 = *(const float4*)&upv[tx * 8 + 4];
        float4 r0, r1;
        r0.x = fmaxf(o[0] + up0.x, 0.f); r0.y = fmaxf(o[1] + up0.y, 0.f);
        r0.z = fmaxf(o[2] + up0.z, 0.f); r0.w = fmaxf(o[3] + up0.w, 0.f);
        r1.x = fmaxf(o[4] + up1.x, 0.f); r1.y = fmaxf(o[5] + up1.y, 0.f);
        r1.z = fmaxf(o[6] + up1.z, 0.f); r1.w = fmaxf(o[7] + up1.w, 0.f);
        float* ctx = out_ctx + ((size_t)(u * II + i0 + ty)) * CC + tx * 8;
        *(float4*)&ctx[0] = r0;
        *(float4*)&ctx[4] = r1;
    }
}

// ---------------------------------------------------------------------------
extern "C" void kernel_launch(void* const* d_in, const int* in_sizes, int n_in,
                              void* d_out, int out_size, void* d_ws,
                              size_t ws_size, hipStream_t stream) {
    const float* tgt  = (const float*)d_in[0];
    const float* itc  = (const float*)d_in[1];
    const float* user = (const float*)d_in[2];
    const int*   mask = (const int*)d_in[3];
    const float* wd   = (const float*)d_in[4];
    const float* bd   = (const float*)d_in[5];
    const float* Wm   = (const float*)d_in[6];
    const float* bm   = (const float*)d_in[7];
    float* out_ctx  = (float*)d_out;
    float* out_attn = out_ctx + (size_t)UU * II * CC;

    size_t scalars = (size_t)(UU * II + UU * JJ + UU * CC) * sizeof(float);
    size_t need = scalars + (size_t)UU * NJT * 8192 * sizeof(short);
    if (ws_size >= need) {
        float* st_g = (float*)d_ws;
        float* sk_g = st_g + UU * II;
        float* up_g = sk_g + UU * JJ;
        short* vt_g = (short*)((char*)d_ws + scalars);
        int gridA = ST_BLOCKS + UP_BLOCKS + VT_BLOCKS;
        precompute_kernel<<<gridA, 256, 0, stream>>>(tgt, itc, user, wd, bd, Wm,
                                                     bm, st_g, sk_g, up_g, vt_g);
        fused_main<<<UU * NIB, 256, 0, stream>>>(mask, Wm, st_g, sk_g, up_g,
                                                 vt_g, out_ctx, out_attn);
    } else {
        fused_fallback<<<UU * NIB, 256, 0, stream>>>(
            tgt, itc, user, mask, wd, bd, Wm, bm, out_ctx, out_attn);
    }
}

// Round 5
// 59.533 us; speedup vs baseline: 5.1997x; 1.8775x over previous
//
#include <hip/hip_runtime.h>

// Problem constants (UserContextAttentionPooler): U=128, I=256, J=512, C=E=128
#define UU 128
#define II 256
#define JJ 512
#define CC 128
#define EE 128
#define IB 16            // i-rows per block
#define NIB 16           // i-tiles per u
#define JT 64            // j per V tile
#define NJT 8            // V tiles per u
#define VTP 72           // (fallback kernel) Vt row stride in shorts

typedef short bf16x8 __attribute__((ext_vector_type(8)));
typedef float f32x4 __attribute__((ext_vector_type(4)));

union FragU { bf16x8 v; unsigned u[4]; };

__device__ __forceinline__ float fast_tanh(float x) {
    float ex = __expf(2.0f * x);
    return 1.0f - 2.0f / (ex + 1.0f);
}

__device__ __forceinline__ unsigned pack_bf16x2(float lo, float hi) {
    unsigned ul = __float_as_uint(lo), uh = __float_as_uint(hi);
    ul = (ul + 0x7FFFu + ((ul >> 16) & 1u)) >> 16;
    uh = (uh + 0x7FFFu + ((uh >> 16) & 1u)) >> 16;
    return ul | (uh << 16);
}

__device__ __forceinline__ short bf16s(float f) {
    unsigned u = __float_as_uint(f);
    u = (u + 0x7FFFu + ((u >> 16) & 1u)) >> 16;
    return (short)u;
}

__device__ __forceinline__ float wave_reduce_add(float v) {
#pragma unroll
    for (int k = 32; k >= 1; k >>= 1) v += __shfl_xor(v, k, 64);
    return v;
}

// ---------------------------------------------------------------------------
// Kernel A: precompute s_t (U,I)[+b_dense], u_part (U,C)[+b_mlp], Vt_g tiles
// (s_k folded into the Vt pass), and wt_g = bf16-packed W_mlp[E:] in B-frag
// order: wt_g[ks*4096 + n*32 + 8g + e] = W[32ks+8g+e][n].
// Vt tile (u,jt), short idx: kk*4096 + c*32 + (j&31); wave B-frag load is a
// contiguous 1KB region. VT blocks remapped so writer XCD == u%8 (consumer).
// ---------------------------------------------------------------------------
#define ST_BLOCKS (UU * II / 4)   // 8192
#define UP_BLOCKS (UU * CC / 256) // 64
#define VT_BLOCKS (UU * NJT)      // 1024

__global__ void precompute_kernel(const float* __restrict__ tgt,
                                  const float* __restrict__ itc,
                                  const float* __restrict__ user,
                                  const float* __restrict__ wd,
                                  const float* __restrict__ bd,
                                  const float* __restrict__ Wm,
                                  const float* __restrict__ bm,
                                  float* __restrict__ st_g,
                                  float* __restrict__ sk_g,
                                  float* __restrict__ up_g,
                                  short* __restrict__ vtg,
                                  short* __restrict__ wtg) {
    __shared__ float vt_f[JT][CC + 4];
    int b = blockIdx.x;
    int t = threadIdx.x;
    if (b < ST_BLOCKS) {
        int row = b * 4 + (t >> 6);
        int lane = t & 63;
        float2 a = *(const float2*)&tgt[(size_t)row * CC + lane * 2];
        float2 w = *(const float2*)&wd[lane * 2];
        float s = wave_reduce_add(a.x * w.x + a.y * w.y);
        if (lane == 0) st_g[row] = s + bd[0];
    } else if (b < ST_BLOCKS + UP_BLOCKS) {
        int idx = (b - ST_BLOCKS) * 256 + t;
        int u = idx >> 7, c = idx & 127;
        float acc = bm[c];
#pragma unroll 8
        for (int e = 0; e < EE; ++e) acc += user[u * EE + e] * Wm[e * CC + c];
        up_g[idx] = acc;
    } else if (b < ST_BLOCKS + UP_BLOCKS + VT_BLOCKS) {
        int vb = b - ST_BLOCKS - UP_BLOCKS;
        int u = vb & 127, jt = vb >> 7;   // u fast -> writer XCD = u%8
        const float* src = itc + ((size_t)u * JJ + jt * JT) * CC;
#pragma unroll
        for (int k = 0; k < 8; ++k) {
            int f = t + 256 * k;
            int row = f >> 5, c4 = (f & 31) * 4;
            *(float4*)&vt_f[row][c4] = *(const float4*)&src[(size_t)row * CC + c4];
        }
        __syncthreads();
        // s_k for these 64 rows (4 threads per row)
        {
            int r = t >> 2, q4 = t & 3;
            float s = 0.f;
#pragma unroll
            for (int cc = 0; cc < 32; cc += 4) {
                float4 a = *(const float4*)&vt_f[r][q4 * 32 + cc];
                float4 w = *(const float4*)&wd[CC + q4 * 32 + cc];
                s += a.x * w.x + a.y * w.y + a.z * w.z + a.w * w.w;
            }
            s += __shfl_xor(s, 1, 64);
            s += __shfl_xor(s, 2, 64);
            if (q4 == 0) sk_g[u * JJ + jt * JT + r] = s;
        }
        // pack transposed bf16 tile: [kk][c][j&31]
        {
            int c = t & 127, half = t >> 7;
            unsigned* dst = (unsigned*)(vtg + (size_t)(u * NJT + jt) * 8192) +
                            half * 2048 + c * 16;
#pragma unroll
            for (int m = 0; m < 16; ++m) {
                dst[m] = pack_bf16x2(vt_f[32 * half + 2 * m][c],
                                     vt_f[32 * half + 2 * m + 1][c]);
            }
        }
    } else {
        // pack W_mlp[E:] (128x128) -> wt_g, B-frag order
        int n = t & 127, khalf = t >> 7;
#pragma unroll
        for (int ks2 = 0; ks2 < 2; ++ks2) {
            int ks = khalf * 2 + ks2;
#pragma unroll
            for (int g = 0; g < 4; ++g) {
                unsigned q[4];
#pragma unroll
                for (int pr = 0; pr < 4; ++pr) {
                    float lo = Wm[(size_t)(EE + 32 * ks + 8 * g + 2 * pr) * CC + n];
                    float hi = Wm[(size_t)(EE + 32 * ks + 8 * g + 2 * pr + 1) * CC + n];
                    q[pr] = pack_bf16x2(lo, hi);
                }
                *(uint4*)&wtg[ks * 4096 + n * 32 + 8 * g] =
                    make_uint4(q[0], q[1], q[2], q[3]);
            }
        }
    }
}

// ---------------------------------------------------------------------------
// Kernel B (main): one block per (u, 16-row i-tile), 256 threads = 4 waves.
// Phase1 dedup'd p -> swizzled bf16 LDS + f32 attn write from regs.
// Phase3: MFMA with explicit 8-deep register prefetch of B from L2-hot vt_g.
// Phase5: mlp via MFMA (pooled bf16 in swizzled LDS x wt_g B-frags).
// ---------------------------------------------------------------------------
__global__ __launch_bounds__(256, 4) void fused_main(
    const int* __restrict__ mask, const float* __restrict__ st_g,
    const float* __restrict__ sk_g, const float* __restrict__ up_g,
    const short* __restrict__ vt_g, const short* __restrict__ wt_g,
    float* __restrict__ out_ctx, float* __restrict__ out_attn) {
    __shared__ __align__(16) short ps[8192];       // 16KB p tile (swizzled)
    __shared__ __align__(16) short pooled_bf[2048];// 4KB pooled tile (swizzled)
    __shared__ float dinv_lds[IB];

    int b = blockIdx.x;
    int x = b & 7, qq = b >> 3;
    int u = x + 8 * (qq >> 4);     // 16 blocks of a given u -> same XCD
    int ib = qq & 15;
    int i0 = ib * IB;
    int t = threadIdx.x;
    int w = t >> 6, l = t & 63, ln = l & 15, g = l >> 4;

    // ---- Phase 1: p once per block; 32 elems/thread (row r, seg s4) ----
    int r = t >> 4, s4 = t & 15;
    float sv = st_g[u * II + i0 + r];
    const float* skb = sk_g + u * JJ;
    const int* mkb = mask + u * JJ;
    float pf[32];
    float rowsum = 0.f;
#pragma unroll
    for (int h = 0; h < 4; ++h) {
        int jb = 8 * (s4 + 16 * h);
        float4 k0 = *(const float4*)&skb[jb];
        float4 k1 = *(const float4*)&skb[jb + 4];
        int4 m0 = *(const int4*)&mkb[jb];
        int4 m1 = *(const int4*)&mkb[jb + 4];
        float* pp = pf + 8 * h;
        pp[0] = m0.x ? __expf(fast_tanh(sv + k0.x)) : 0.f;
        pp[1] = m0.y ? __expf(fast_tanh(sv + k0.y)) : 0.f;
        pp[2] = m0.z ? __expf(fast_tanh(sv + k0.z)) : 0.f;
        pp[3] = m0.w ? __expf(fast_tanh(sv + k0.w)) : 0.f;
        pp[4] = m1.x ? __expf(fast_tanh(sv + k1.x)) : 0.f;
        pp[5] = m1.y ? __expf(fast_tanh(sv + k1.y)) : 0.f;
        pp[6] = m1.z ? __expf(fast_tanh(sv + k1.z)) : 0.f;
        pp[7] = m1.w ? __expf(fast_tanh(sv + k1.w)) : 0.f;
        rowsum += pp[0] + pp[1] + pp[2] + pp[3] + pp[4] + pp[5] + pp[6] + pp[7];
        unsigned q0 = pack_bf16x2(pp[0], pp[1]);
        unsigned q1 = pack_bf16x2(pp[2], pp[3]);
        unsigned q2 = pack_bf16x2(pp[4], pp[5]);
        unsigned q3 = pack_bf16x2(pp[6], pp[7]);
        int gp = (s4 + 16 * h) ^ (r & 7);
        *(uint4*)((char*)ps + r * 1024 + 16 * gp) = make_uint4(q0, q1, q2, q3);
    }
    rowsum += __shfl_xor(rowsum, 1, 64);
    rowsum += __shfl_xor(rowsum, 2, 64);
    rowsum += __shfl_xor(rowsum, 4, 64);
    rowsum += __shfl_xor(rowsum, 8, 64);
    float dinv = 1.0f / rowsum;
    if (s4 == 0) dinv_lds[r] = dinv;

    // ---- Phase 2: attn write (dedup'd, f32 from regs) ----
    {
        float* ab = out_attn + ((size_t)(u * II + i0 + r)) * JJ;
#pragma unroll
        for (int h = 0; h < 4; ++h) {
            int jb = 8 * (s4 + 16 * h);
            const float* pp = pf + 8 * h;
            *(float4*)&ab[jb] =
                make_float4(pp[0] * dinv, pp[1] * dinv, pp[2] * dinv, pp[3] * dinv);
            *(float4*)&ab[jb + 4] =
                make_float4(pp[4] * dinv, pp[5] * dinv, pp[6] * dinv, pp[7] * dinv);
        }
    }

    // ---- Phase 3 prefetch: 8-deep B-frag pipeline (issued pre-barrier) ----
    const short* b_base =
        vt_g + (size_t)u * (NJT * 8192) + (32 * w + ln) * 32 + 8 * g;
    bf16x8 pb0[8], pb1[8];
#pragma unroll
    for (int s = 0; s < 8; ++s) {
        int off = (s >> 1) * 8192 + (s & 1) * 4096;
        pb0[s] = *(const bf16x8*)&b_base[off];
        pb1[s] = *(const bf16x8*)&b_base[off + 512];
    }

    // LDS-only barrier (no vmcnt drain: attn stores + prefetch stay in flight)
    asm volatile("s_waitcnt lgkmcnt(0)" ::: "memory");
    __builtin_amdgcn_s_barrier();
    asm volatile("" ::: "memory");

    // ---- Phase 3: 16 MFMA steps, 8-deep register pipeline ----
    f32x4 acc0 = {0.f, 0.f, 0.f, 0.f};
    f32x4 acc1 = {0.f, 0.f, 0.f, 0.f};
#pragma unroll
    for (int s = 0; s < 16; ++s) {
        bf16x8 af = *(const bf16x8*)((const char*)ps + ln * 1024 +
                                     16 * ((4 * s + g) ^ (ln & 7)));
        acc0 = __builtin_amdgcn_mfma_f32_16x16x32_bf16(af, pb0[s & 7], acc0, 0, 0, 0);
        acc1 = __builtin_amdgcn_mfma_f32_16x16x32_bf16(af, pb1[s & 7], acc1, 0, 0, 0);
        if (s < 8) {
            int off = ((s + 8) >> 1) * 8192 + ((s + 8) & 1) * 4096;
            pb0[s & 7] = *(const bf16x8*)&b_base[off];
            pb1[s & 7] = *(const bf16x8*)&b_base[off + 512];
        }
    }

    // ---- Phase 5 W-frag prefetch (L2-hot 32KB, shared by all blocks) ----
    const short* wbase = wt_g + (32 * w + ln) * 32 + 8 * g;
    bf16x8 wb0[4], wb1[4];
#pragma unroll
    for (int ks = 0; ks < 4; ++ks) {
        wb0[ks] = *(const bf16x8*)&wbase[ks * 4096];
        wb1[ks] = *(const bf16x8*)&wbase[ks * 4096 + 512];
    }

    // ---- Phase 4: scale pooled by dinv, pack bf16 -> swizzled LDS ----
#pragma unroll
    for (int ri = 0; ri < 4; ++ri) {
        int row = 4 * g + ri;
        float dv = dinv_lds[row];
        int c0 = 32 * w + ln;
        int by0 = row * 256 + 16 * ((c0 >> 3) ^ (row & 7)) + 2 * (ln & 7);
        *(short*)((char*)pooled_bf + by0) = bf16s(acc0[ri] * dv);
        int c1 = c0 + 16;
        int by1 = row * 256 + 16 * ((c1 >> 3) ^ (row & 7)) + 2 * (ln & 7);
        *(short*)((char*)pooled_bf + by1) = bf16s(acc1[ri] * dv);
    }
    asm volatile("s_waitcnt lgkmcnt(0)" ::: "memory");
    __builtin_amdgcn_s_barrier();
    asm volatile("" ::: "memory");

    // ---- Phase 5: out = relu(u_part + pooled @ W_mlp[E:]) via MFMA ----
    f32x4 oa0 = {0.f, 0.f, 0.f, 0.f};
    f32x4 oa1 = {0.f, 0.f, 0.f, 0.f};
#pragma unroll
    for (int ks = 0; ks < 4; ++ks) {
        bf16x8 pa = *(const bf16x8*)((const char*)pooled_bf + ln * 256 +
                                     16 * ((4 * ks + g) ^ (ln & 7)));
        oa0 = __builtin_amdgcn_mfma_f32_16x16x32_bf16(pa, wb0[ks], oa0, 0, 0, 0);
        oa1 = __builtin_amdgcn_mfma_f32_16x16x32_bf16(pa, wb1[ks], oa1, 0, 0, 0);
    }
    {
        int c0 = 32 * w + ln, c1 = c0 + 16;
        float up0v = up_g[u * CC + c0];
        float up1v = up_g[u * CC + c1];
        float* ctx = out_ctx + ((size_t)(u * II + i0)) * CC;
#pragma unroll
        for (int ri = 0; ri < 4; ++ri) {
            int row = 4 * g + ri;
            ctx[(size_t)row * CC + c0] = fmaxf(oa0[ri] + up0v, 0.f);
            ctx[(size_t)row * CC + c1] = fmaxf(oa1[ri] + up1v, 0.f);
        }
    }
}

// ---------------------------------------------------------------------------
// Fallback (ws too small): round-2 validated self-contained kernel.
// ---------------------------------------------------------------------------
__global__ __launch_bounds__(256, 3) void fused_fallback(
    const float* __restrict__ tgt, const float* __restrict__ itc,
    const float* __restrict__ user, const int* __restrict__ mask,
    const float* __restrict__ wd, const float* __restrict__ bd,
    const float* __restrict__ Wm, const float* __restrict__ bm,
    float* __restrict__ out_ctx, float* __restrict__ out_attn) {
    __shared__ __align__(16) short Vt[CC][VTP];
    __shared__ __align__(16) float pool[IB][CC + 4];
    __shared__ __align__(16) float skv[JJ];
    __shared__ __align__(16) float stv[IB];
    __shared__ __align__(16) float upv[CC];
    __shared__ __align__(16) float dinv_lds[IB];
    __shared__ unsigned char mk[JJ];

    int b = blockIdx.x;
    int x = b & 7, q = b >> 3;
    int u = x + 8 * (q >> 4);
    int ib = q & 15;
    int i0 = ib * IB;
    int t = threadIdx.x;

    mk[t] = (unsigned char)(mask[u * JJ + t] != 0);
    mk[t + 256] = (unsigned char)(mask[u * JJ + t + 256] != 0);

    {
        int lane = t & 63, w4 = t >> 6;
        float2 w2 = *(const float2*)&wd[CC + lane * 2];
        for (int r = w4; r < JJ; r += 4) {
            float2 a = *(const float2*)&itc[((size_t)u * JJ + r) * CC + lane * 2];
            float s = wave_reduce_add(a.x * w2.x + a.y * w2.y);
            if (lane == 0) skv[r] = s;
        }
        float2 w1 = *(const float2*)&wd[lane * 2];
        float bdv = bd[0];
        for (int r = w4; r < IB; r += 4) {
            float2 a = *(const float2*)&tgt[((size_t)u * II + i0 + r) * CC + lane * 2];
            float s = wave_reduce_add(a.x * w1.x + a.y * w1.y);
            if (lane == 0) stv[r] = s + bdv;
        }
        if (t < CC) {
            float acc = bm[t];
            for (int e = 0; e < EE; ++e) acc += user[u * EE + e] * Wm[e * CC + t];
            upv[t] = acc;
        }
    }
    __syncthreads();

    const int l = t & 63;
    const int w = t >> 6;
    const int ln = l & 15;
    const int g = l >> 4;

    bf16x8 a[16];
    float rowsum = 0.0f;
    {
        float s = stv[ln];
#pragma unroll
        for (int t16 = 0; t16 < 16; ++t16) {
            int j = 32 * t16 + 8 * g;
            float4 k0 = *(const float4*)&skv[j];
            float4 k1 = *(const float4*)&skv[j + 4];
            unsigned m0 = *(const unsigned*)&mk[j];
            unsigned m1 = *(const unsigned*)&mk[j + 4];
            float pf[8];
            pf[0] = (m0 & 0x000000FFu) ? __expf(fast_tanh(s + k0.x)) : 0.0f;
            pf[1] = (m0 & 0x0000FF00u) ? __expf(fast_tanh(s + k0.y)) : 0.0f;
            pf[2] = (m0 & 0x00FF0000u) ? __expf(fast_tanh(s + k0.z)) : 0.0f;
            pf[3] = (m0 & 0xFF000000u) ? __expf(fast_tanh(s + k0.w)) : 0.0f;
            pf[4] = (m1 & 0x000000FFu) ? __expf(fast_tanh(s + k1.x)) : 0.0f;
            pf[5] = (m1 & 0x0000FF00u) ? __expf(fast_tanh(s + k1.y)) : 0.0f;
            pf[6] = (m1 & 0x00FF0000u) ? __expf(fast_tanh(s + k1.z)) : 0.0f;
            pf[7] = (m1 & 0xFF000000u) ? __expf(fast_tanh(s + k1.w)) : 0.0f;
            rowsum += pf[0] + pf[1] + pf[2] + pf[3] + pf[4] + pf[5] + pf[6] + pf[7];
            FragU cu;
            cu.u[0] = pack_bf16x2(pf[0], pf[1]);
            cu.u[1] = pack_bf16x2(pf[2], pf[3]);
            cu.u[2] = pack_bf16x2(pf[4], pf[5]);
            cu.u[3] = pack_bf16x2(pf[6], pf[7]);
            a[t16] = cu.v;
        }
    }
    rowsum += __shfl_xor(rowsum, 16, 64);
    rowsum += __shfl_xor(rowsum, 32, 64);
    float dinv = 1.0f / rowsum;
    if (t < 16) dinv_lds[t] = dinv;

    {
        float* abase = out_attn + ((size_t)(u * II + i0 + ln)) * JJ + 8 * g;
#pragma unroll
        for (int t16 = 0; t16 < 16; ++t16) {
            FragU cu; cu.v = a[t16];
            float f0 = __uint_as_float(cu.u[0] << 16) * dinv;
            float f1 = __uint_as_float(cu.u[0] & 0xFFFF0000u) * dinv;
            float f2 = __uint_as_float(cu.u[1] << 16) * dinv;
            float f3 = __uint_as_float(cu.u[1] & 0xFFFF0000u) * dinv;
            float f4 = __uint_as_float(cu.u[2] << 16) * dinv;
            float f5 = __uint_as_float(cu.u[2] & 0xFFFF0000u) * dinv;
            float f6 = __uint_as_float(cu.u[3] << 16) * dinv;
            float f7 = __uint_as_float(cu.u[3] & 0xFFFF0000u) * dinv;
            *(float4*)&abase[32 * t16] = make_float4(f0, f1, f2, f3);
            *(float4*)&abase[32 * t16 + 4] = make_float4(f4, f5, f6, f7);
        }
    }

    f32x4 acc0 = {0.f, 0.f, 0.f, 0.f};
    f32x4 acc1 = {0.f, 0.f, 0.f, 0.f};
    const float* Vu = itc + (size_t)u * JJ * CC;
    const int cg = t & 31;
    const int jp = t >> 5;
    const int n0 = w * 32;

    for (int jt = 0; jt < 8; ++jt) {
        int j0 = jt * JT;
        __syncthreads();
#pragma unroll
        for (int it = 0; it < 4; ++it) {
            int jl = 2 * (jp + 8 * it);
            const float* r0 = &Vu[(size_t)(j0 + jl) * CC];
            const float* r1 = r0 + CC;
#pragma unroll
            for (int qv = 0; qv < 4; ++qv) {
                int c = cg + 32 * qv;
                *(unsigned*)&Vt[c][jl] = pack_bf16x2(r0[c], r1[c]);
            }
        }
        __syncthreads();
#pragma unroll
        for (int kk = 0; kk < 2; ++kk) {
            bf16x8 b0 = *(const bf16x8*)&Vt[n0 + ln][32 * kk + 8 * g];
            bf16x8 b1 = *(const bf16x8*)&Vt[n0 + 16 + ln][32 * kk + 8 * g];
            acc0 = __builtin_amdgcn_mfma_f32_16x16x32_bf16(a[2 * jt + kk], b0,
                                                           acc0, 0, 0, 0);
            acc1 = __builtin_amdgcn_mfma_f32_16x16x32_bf16(a[2 * jt + kk], b1,
                                                           acc1, 0, 0, 0);
        }
    }

    __syncthreads();
    {
        float4 dv = *(const float4*)&dinv_lds[4 * g];
        float dvr[4] = {dv.x, dv.y, dv.z, dv.w};
#pragma unroll
        for (int r = 0; r < 4; ++r) {
            pool[4 * g + r][n0 + ln] = acc0[r] * dvr[r];
            pool[4 * g + r][n0 + 16 + ln] = acc1[r] * dvr[r];
        }
    }
    __syncthreads();

    {
        int tx = t & 15, ty = t >> 4;
        float o[8];
#pragma unroll
        for (int k = 0; k < 8; ++k) o[k] = 0.f;
#pragma unroll 4
        for (int k = 0; k < CC; ++k) {
            float pk = pool[ty][k];
            float4 w0 = *(const float4*)&Wm[(size_t)(EE + k) * CC + tx * 8];
            float4 w1 = *(const float4*)&Wm[(size_t)(EE + k) * CC + tx * 8 + 4];
            o[0] += pk * w0.x; o[1] += pk * w0.y; o[2] += pk * w0.z; o[3] += pk * w0.w;
            o[4] += pk * w1.x; o[5] += pk * w1.y; o[6] += pk * w1.z; o[7] += pk * w1.w;
        }
        float4 up0 = *(const float4*)&upv[tx * 8];
        float4 up1 = *(const float4*)&upv[tx * 8 + 4];
        float4 r0, r1;
        r0.x = fmaxf(o[0] + up0.x, 0.f); r0.y = fmaxf(o[1] + up0.y, 0.f);
        r0.z = fmaxf(o[2] + up0.z, 0.f); r0.w = fmaxf(o[3] + up0.w, 0.f);
        r1.x = fmaxf(o[4] + up1.x, 0.f); r1.y = fmaxf(o[5] + up1.y, 0.f);
        r1.z = fmaxf(o[6] + up1.z, 0.f); r1.w = fmaxf(o[7] + up1.w, 0.f);
        float* ctx = out_ctx + ((size_t)(u * II + i0 + ty)) * CC + tx * 8;
        *(float4*)&ctx[0] = r0;
        *(float4*)&ctx[4] = r1;
    }
}

// ---------------------------------------------------------------------------
extern "C" void kernel_launch(void* const* d_in, const int* in_sizes, int n_in,
                              void* d_out, int out_size, void* d_ws,
                              size_t ws_size, hipStream_t stream) {
    const float* tgt  = (const float*)d_in[0];
    const float* itc  = (const float*)d_in[1];
    const float* user = (const float*)d_in[2];
    const int*   mask = (const int*)d_in[3];
    const float* wd   = (const float*)d_in[4];
    const float* bd   = (const float*)d_in[5];
    const float* Wm   = (const float*)d_in[6];
    const float* bm   = (const float*)d_in[7];
    float* out_ctx  = (float*)d_out;
    float* out_attn = out_ctx + (size_t)UU * II * CC;

    size_t scalars = (size_t)(UU * II + UU * JJ + UU * CC) * sizeof(float);
    size_t vt_bytes = (size_t)UU * NJT * 8192 * sizeof(short);
    size_t wt_bytes = (size_t)16384 * sizeof(short);
    size_t need = scalars + vt_bytes + wt_bytes;
    if (ws_size >= need) {
        float* st_g = (float*)d_ws;
        float* sk_g = st_g + UU * II;
        float* up_g = sk_g + UU * JJ;
        short* vt_g = (short*)((char*)d_ws + scalars);
        short* wt_g = vt_g + (size_t)UU * NJT * 8192;
        int gridA = ST_BLOCKS + UP_BLOCKS + VT_BLOCKS + 1;
        precompute_kernel<<<gridA, 256, 0, stream>>>(
            tgt, itc, user, wd, bd, Wm, bm, st_g, sk_g, up_g, vt_g, wt_g);
        fused_main<<<UU * NIB, 256, 0, stream>>>(mask, st_g, sk_g, up_g, vt_g,
                                                 wt_g, out_ctx, out_attn);
    } else {
        fused_fallback<<<UU * NIB, 256, 0, stream>>>(
            tgt, itc, user, mask, wd, bd, Wm, bm, out_ctx, out_attn);
    }
}